// Round 10
// baseline (126.346 us; speedup 1.0000x reference)
//
#include <hip/hip_runtime.h>
#include <hip/hip_bf16.h>
#include <math.h>

#define BB   32
#define CC   512
#define NPIX 1600
#define KK   64
#define NTILE 50       // 32-n tiles in pass A
#define NT2  100       // asum partial slots = NTILE * 2 (ng halves)
#define EPSF 1e-12f

typedef __attribute__((ext_vector_type(8))) short bf16x8;
typedef __attribute__((ext_vector_type(4))) float f32x4;
#define MFMA16 __builtin_amdgcn_mfma_f32_16x16x32_bf16

__device__ __forceinline__ ushort f2bf(float f) {
    __hip_bfloat16 h = __float2bfloat16(f);       // RNE, HW cvt
    return *reinterpret_cast<ushort*>(&h);
}
__device__ __forceinline__ uint pk2bf(float a, float b) {
    return (uint)f2bf(a) | ((uint)f2bf(b) << 16);
}

// ---------------------------------------------------------------------------
// k_wprep: w_bf16[k][c] = bf16(w[k][c])   (one-time, 64 KB out)
// ---------------------------------------------------------------------------
__global__ __launch_bounds__(256) void k_wprep(const float* __restrict__ w,
                                               ushort* __restrict__ wb) {
    int i = blockIdx.x * 256 + threadIdx.x;       // over KK*CC/2 = 16384 pairs
    float2 v = *(const float2*)&w[(size_t)i * 2];
    ((uint*)wb)[i] = pk2bf(v.x, v.y);
}

// ---------------------------------------------------------------------------
// k_gemm1m: per (32n tile, b), 256 thr = 4 waves = 2 n-groups x 2 c-halves.
// Wave (ng,ch): D[64k][16n] partial over its 256-c half; 8 steps of 64c
// staged (transposed+cvt) into dbuf LDS; A-frags direct from wb (L2).
// Epilogue: ch=1 waves dump acc to LDS, ch=0 adds -> full logits; softmax
// (invn-scaled) -> a_t[b][k][n] bf16 + asum partials.
// Xs layout: row n (32 words = 64 c bf16-pairs), word col' = ((cp>>2)^(n&7))<<2 | (cp&3):
//   writes lane==col-aligned (2-way, free), b128 reads 2-way (free).
// ---------------------------------------------------------------------------
__global__ __launch_bounds__(256) void k_gemm1m(const float* __restrict__ x,
                                                const ushort* __restrict__ wb,
                                                ushort* __restrict__ a_t,
                                                float* __restrict__ asum_p) {
    int tile = blockIdx.x, b = blockIdx.y;
    int n0 = tile * 32;
    int t = threadIdx.x, lane = t & 63, wv = t >> 6;
    int ng = wv & 1, ch = wv >> 1;
    int nlo = lane & 15, khi = lane >> 4;
    __shared__ __align__(16) uint  Xs[2][32 * 32];   // [buf][n][32 swz words]
    __shared__ __align__(16) float Cmb[2 * 64 * 17]; // [ng][lane][16+pad]
    __shared__ float ssq_s[32];
    const float* xb = x + (size_t)b * CC * NPIX + n0;
    f32x4 acc[4] = {};
    float ssp[4] = {0.f, 0.f, 0.f, 0.f};
    int scp = t & 31;              // staged c-pair 0..31 (c = 2*scp within 64-c step)
    int sn4 = (t >> 5) * 4;        // staged n base

    float4 fe, fo;
#define LOADS(st_)                                                          \
    {                                                                       \
        int cg_ = (st_) * 64 + scp * 2;                                     \
        fe = *(const float4*)&xb[(size_t)cg_ * NPIX + sn4];                 \
        fo = *(const float4*)&xb[(size_t)(cg_ + 1) * NPIX + sn4];           \
    }
#define STORES(st_)                                                         \
    {                                                                       \
        uint* X_ = Xs[(st_) & 1];                                           \
        float fa_[4] = {fe.x, fe.y, fe.z, fe.w};                            \
        float fb_[4] = {fo.x, fo.y, fo.z, fo.w};                            \
        _Pragma("unroll")                                                   \
        for (int j = 0; j < 4; ++j) {                                       \
            ssp[j] = fmaf(fa_[j], fa_[j], fmaf(fb_[j], fb_[j], ssp[j]));    \
            int row_ = sn4 + j;                                             \
            int col_ = (((scp >> 2) ^ (row_ & 7)) << 2) | (scp & 3);        \
            X_[row_ * 32 + col_] = pk2bf(fa_[j], fb_[j]);                   \
        }                                                                   \
    }

    LOADS(0); STORES(0);
    __syncthreads();
    int nloc = ng * 16 + nlo;
    int colB = (((ch * 4 + khi) ^ (nloc & 7)) << 2);
#pragma unroll
    for (int st = 0; st < 8; ++st) {
        if (st < 7) LOADS(st + 1);
        {   // compute step st from Xs[st&1]
            const uint* X_ = Xs[st & 1];
            bf16x8 bfr = *(const bf16x8*)&X_[nloc * 32 + colB];
            int cb = st * 64 + ch * 32;
#pragma unroll
            for (int kf = 0; kf < 4; ++kf) {
                bf16x8 afr = *(const bf16x8*)
                    &wb[(size_t)(kf * 16 + nlo) * CC + cb + khi * 8];
                acc[kf] = MFMA16(afr, bfr, acc[kf], 0, 0, 0);
            }
        }
        if (st < 7) STORES(st + 1);
        __syncthreads();
    }
#undef LOADS
#undef STORES

    // ssq: butterfly over the 32 threads of each n-quad group (same wave half)
#pragma unroll
    for (int off = 1; off < 32; off <<= 1)
#pragma unroll
        for (int j = 0; j < 4; ++j) ssp[j] += __shfl_xor(ssp[j], off);
    if ((t & 31) == 0) {
#pragma unroll
        for (int j = 0; j < 4; ++j) ssq_s[sn4 + j] = ssp[j];
    }

    // c-half combine: ch=1 dumps acc, barrier, ch=0 adds
    if (ch == 1) {
        float* C_ = &Cmb[(ng * 64 + lane) * 17];
#pragma unroll
        for (int kf = 0; kf < 4; ++kf)
#pragma unroll
            for (int r = 0; r < 4; ++r) C_[kf * 4 + r] = acc[kf][r];
    }
    __syncthreads();
    if (ch == 1) return;
    {
        const float* C_ = &Cmb[(ng * 64 + lane) * 17];
#pragma unroll
        for (int kf = 0; kf < 4; ++kf)
#pragma unroll
            for (int r = 0; r < 4; ++r) acc[kf][r] += C_[kf * 4 + r];
    }

    float invl = 1.f / fmaxf(sqrtf(ssq_s[nloc]), EPSF);

    // softmax over k (lane holds 16 k's for one n; combine khi groups)
    float lv[4][4];
    float mm = -1e30f;
#pragma unroll
    for (int kf = 0; kf < 4; ++kf)
#pragma unroll
        for (int r = 0; r < 4; ++r) {
            lv[kf][r] = acc[kf][r] * invl;
            mm = fmaxf(mm, lv[kf][r]);
        }
    mm = fmaxf(mm, __shfl_xor(mm, 16));
    mm = fmaxf(mm, __shfl_xor(mm, 32));
    float ev[4][4], s = 0.f;
#pragma unroll
    for (int kf = 0; kf < 4; ++kf)
#pragma unroll
        for (int r = 0; r < 4; ++r) {
            ev[kf][r] = expf(lv[kf][r] - mm);
            s += ev[kf][r];
        }
    s += __shfl_xor(s, 16);
    s += __shfl_xor(s, 32);
    float sd = 1.f / s;

    // asum partials (unscaled a): reduce over this wave's 16 n
    float av[4][4];
#pragma unroll
    for (int kf = 0; kf < 4; ++kf)
#pragma unroll
        for (int r = 0; r < 4; ++r) av[kf][r] = ev[kf][r] * sd;
#pragma unroll
    for (int off = 1; off < 16; off <<= 1)
#pragma unroll
        for (int kf = 0; kf < 4; ++kf)
#pragma unroll
            for (int r = 0; r < 4; ++r) av[kf][r] += __shfl_xor(av[kf][r], off);
    if (nlo == 0) {
#pragma unroll
        for (int kf = 0; kf < 4; ++kf)
#pragma unroll
            for (int r = 0; r < 4; ++r) {
                int k = kf * 16 + khi * 4 + r;
                asum_p[((size_t)b * KK + k) * NT2 + tile * 2 + ng] = av[kf][r];
            }
    }

    // a' = a * invn -> a_t[b][k][n] bf16
    ushort* ab = a_t + (size_t)b * KK * NPIX;
#pragma unroll
    for (int kf = 0; kf < 4; ++kf)
#pragma unroll
        for (int r = 0; r < 4; ++r) {
            int k = kf * 16 + khi * 4 + r;
            ab[(size_t)k * NPIX + n0 + nloc] = f2bf(ev[kf][r] * sd * invl);
        }
}

// ---------------------------------------------------------------------------
// k_vladm: part[s][b][k][c] = sum_{n in chunk} a'[k,n] * x[c,n]   (MFMA)
// LDS-free: A-frag = uint4 from a_t[b][k][n]; B-frag = 2x float4 from x + cvt.
// grid (ns, BB, 8): linear id = s + ns*b + ns*32*cx -> the 8 c-tiles of one
// (s,b) share an XCD (id mod 8 equal) for a_t L2 reuse.
// ---------------------------------------------------------------------------
__global__ __launch_bounds__(256) void k_vladm(const ushort* __restrict__ a_t,
                                               const float* __restrict__ x,
                                               float* __restrict__ part,
                                               int nchunk) {
    int s  = blockIdx.x;
    int b  = blockIdx.y;
    int c0 = blockIdx.z * 64;
    int t = threadIdx.x, lane = t & 63, wv = t >> 6;
    int clo = lane & 15, nhi = lane >> 4;
    int rc = wv * 16 + clo;                        // this lane's c-column
    const ushort* ab = a_t + (size_t)b * KK * NPIX;
    const float*  xr = x + (size_t)b * CC * NPIX + (size_t)(c0 + rc) * NPIX;
    f32x4 acc[4] = {};
    int nbase = s * nchunk, niters = nchunk / 32;

#pragma unroll 2
    for (int it = 0; it < niters; ++it) {
        int nb = nbase + it * 32 + nhi * 8;
        float4 x0 = *(const float4*)&xr[nb];
        float4 x1 = *(const float4*)&xr[nb + 4];
        uint4 bp;
        bp.x = pk2bf(x0.x, x0.y); bp.y = pk2bf(x0.z, x0.w);
        bp.z = pk2bf(x1.x, x1.y); bp.w = pk2bf(x1.z, x1.w);
        bf16x8 bfr = *reinterpret_cast<bf16x8*>(&bp);
#pragma unroll
        for (int kf = 0; kf < 4; ++kf) {
            int rk = kf * 16 + clo;
            bf16x8 afr = *(const bf16x8*)&ab[(size_t)rk * NPIX + nb];
            acc[kf] = MFMA16(afr, bfr, acc[kf], 0, 0, 0);
        }
    }

#pragma unroll
    for (int kf = 0; kf < 4; ++kf)
#pragma unroll
        for (int r = 0; r < 4; ++r) {
            int k = kf * 16 + nhi * 4 + r;
            part[(((size_t)s * BB + b) * KK + k) * CC + c0 + rc] = acc[kf][r];
        }
}

// ---------------------------------------------------------------------------
// k_asum: asum[row] = sum_i asum_p[row][i]   (row = b*KK+k, i < NT2)
// ---------------------------------------------------------------------------
__global__ __launch_bounds__(256) void k_asum(const float* __restrict__ asum_p,
                                              float* __restrict__ asum) {
    int row = blockIdx.x * 256 + threadIdx.x;     // 2048 rows exact
    const float* p = asum_p + (size_t)row * NT2;
    float s = 0.f;
#pragma unroll 4
    for (int i = 0; i < NT2; ++i) s += p[i];
    asum[row] = s;
}

// ---------------------------------------------------------------------------
// k_intra: sum ns partials, subtract asum*cent, intra-normalize per (b,k),
// accumulate per-b sum of squares.
// ---------------------------------------------------------------------------
__global__ __launch_bounds__(256) void k_intra(const float* __restrict__ part, int ns,
                                               const float* __restrict__ asum,
                                               const float* __restrict__ cent,
                                               float* __restrict__ out,
                                               float* __restrict__ bsum) {
    int row = blockIdx.x;                          // b*KK + k
    int b = row >> 6, k = row & 63;
    int t = threadIdx.x;
    float v0 = 0.f, v1 = 0.f;
    for (int s2 = 0; s2 < ns; ++s2) {
        const float* p = part + (((size_t)s2 * BB + b) * KK + k) * CC;
        v0 += p[t];
        v1 += p[t + 256];
    }
    float as = asum[row];
    v0 -= as * cent[k * CC + t];
    v1 -= as * cent[k * CC + t + 256];
    float ssq = v0 * v0 + v1 * v1;
#pragma unroll
    for (int off = 32; off; off >>= 1) ssq += __shfl_down(ssq, off, 64);
    __shared__ float red[4];
    __shared__ float s_inv;
    if ((t & 63) == 0) red[t >> 6] = ssq;
    __syncthreads();
    if (t == 0) {
        float sm = red[0] + red[1] + red[2] + red[3];
        float inv = 1.f / fmaxf(sqrtf(sm), EPSF);
        s_inv = inv;
        atomicAdd(&bsum[b], sm * inv * inv);
    }
    __syncthreads();
    float inv = s_inv;
    out[(size_t)row * CC + t]       = v0 * inv;
    out[(size_t)row * CC + t + 256] = v1 * inv;
}

// ---------------------------------------------------------------------------
__global__ __launch_bounds__(256) void k_scale(float* __restrict__ out,
                                               const float* __restrict__ bsum) {
    int idx = blockIdx.x * 256 + threadIdx.x;      // B*K*C exact
    int b = idx >> 15;                             // K*C = 32768
    out[idx] *= 1.f / fmaxf(sqrtf(bsum[b]), EPSF);
}

// ---------------------------------------------------------------------------
extern "C" void kernel_launch(void* const* d_in, const int* in_sizes, int n_in,
                              void* d_out, int out_size, void* d_ws, size_t ws_size,
                              hipStream_t stream) {
    const float* x    = (const float*)d_in[0];   // [B,C,H,W]
    const float* cent = (const float*)d_in[1];   // [K,C]
    const float* w    = (const float*)d_in[2];   // [K,C]
    float* out = (float*)d_out;

    char* wsb = (char*)d_ws;
    const size_t oa_at   = 0;                                   // bf16 B*K*N = 6,553,600 B
    const size_t oa_wb   = oa_at + (size_t)BB * KK * NPIX * 2;  // bf16 K*C   =    65,536 B
    const size_t oa_ap   = oa_wb + (size_t)KK * CC * 2;         // f32 2048*NT2 = 819,200 B
    const size_t oa_as   = oa_ap + (size_t)BB * KK * NT2 * 4;   // f32 2048   =     8,192 B
    const size_t oa_bsum = oa_as + (size_t)BB * KK * 4;         //                    128 B
    const size_t oa_part = oa_bsum + 128;
    ushort* a_t   = (ushort*)(wsb + oa_at);
    ushort* wb    = (ushort*)(wsb + oa_wb);
    float* asum_p = (float*)(wsb + oa_ap);
    float* asum   = (float*)(wsb + oa_as);
    float* bsum   = (float*)(wsb + oa_bsum);

    // pick ns with nchunk = 1600/ns a multiple of 32: {5, 2, 1}
    const size_t pbytes = (size_t)BB * KK * CC * 4;             // 4 MB per partial
    int ns = 0;
    const int cand[3] = {5, 2, 1};
    for (int i = 0; i < 3; ++i) {
        if (oa_part + (size_t)cand[i] * pbytes <= ws_size) { ns = cand[i]; break; }
    }
    float* part = (ns > 0) ? (float*)(wsb + oa_part) : out;     // ns=1 fallback -> d_out
    if (ns == 0) ns = 1;
    int nchunk = NPIX / ns;

    hipMemsetAsync(bsum, 0, BB * sizeof(float), stream);

    k_wprep <<<dim3((KK * CC / 2) / 256), 256, 0, stream>>>(w, wb);
    k_gemm1m<<<dim3(NTILE, BB), 256, 0, stream>>>(x, wb, a_t, asum_p);
    k_vladm <<<dim3(ns, BB, CC / 64), 256, 0, stream>>>(a_t, x, part, nchunk);
    k_asum  <<<dim3(BB * KK / 256), 256, 0, stream>>>(asum_p, asum);
    k_intra <<<dim3(BB * KK), 256, 0, stream>>>(part, ns, asum, cent, out, bsum);
    k_scale <<<dim3((BB * KK * CC) / 256), 256, 0, stream>>>(out, bsum);
}

// Round 11
// 125.929 us; speedup vs baseline: 1.0033x; 1.0033x over previous
//
#include <hip/hip_runtime.h>
#include <hip/hip_bf16.h>
#include <math.h>

#define BB   32
#define CC   512
#define NPIX 1600
#define KK   64
#define NT   25        // 64-wide n-tiles in pass A
#define EPSF 1e-12f

typedef __attribute__((ext_vector_type(8))) short bf16x8;
typedef __attribute__((ext_vector_type(4))) float f32x4;
#define MFMA16 __builtin_amdgcn_mfma_f32_16x16x32_bf16

__device__ __forceinline__ ushort f2bf(float f) {
    __hip_bfloat16 h = __float2bfloat16(f);       // RNE, HW cvt
    return *reinterpret_cast<ushort*>(&h);
}
__device__ __forceinline__ uint pk2bf(float a, float b) {
    return (uint)f2bf(a) | ((uint)f2bf(b) << 16);
}

// ---------------------------------------------------------------------------
// k_wprep: w_bf16[k][c] = bf16(w[k][c])   (one-time, 64 KB out, L2-resident)
// ---------------------------------------------------------------------------
__global__ __launch_bounds__(256) void k_wprep(const float* __restrict__ w,
                                               ushort* __restrict__ wb) {
    int i = blockIdx.x * 256 + threadIdx.x;       // over KK*CC/2 = 16384 pairs
    float2 v = *(const float2*)&w[(size_t)i * 2];
    ((uint*)wb)[i] = pk2bf(v.x, v.y);
}

// ---------------------------------------------------------------------------
// k_gemm1m: R7 anchor structure (256 thr, dbuf LDS X-staging) minus W-staging.
// Per (64n tile, b): logits[k][n] = sum_c w[k,c] x[b,c,n] via MFMA 16x16x32;
// ssq from fp32 staging regs -> invn (LDS); softmax over k; a'=a*invn ->
// a_t[b][k][n] bf16; asum_p[b][k][tile].
// A-frag: direct bf16x8 from wb (R8-proven path).  B-frag: Xs LDS, granule-XOR
// swizzled (R7-proven).  One barrier per 32-c step.
// ---------------------------------------------------------------------------
__global__ __launch_bounds__(256) void k_gemm1m(const float* __restrict__ x,
                                                const ushort* __restrict__ wb,
                                                ushort* __restrict__ a_t,
                                                float* __restrict__ asum_p) {
    int tile = blockIdx.x, b = blockIdx.y;
    int n0 = tile * 64;
    __shared__ __align__(16) ushort Xs[2][64 * 32];   // [n][swz c] bf16
    __shared__ __align__(16) float red[16 * 64];
    __shared__ __align__(16) float asw[4 * 64];
    __shared__ __align__(16) float ivs[64];
    int t = threadIdx.x;
    int lane = t & 63, wv = t >> 6;
    int nlo = lane & 15, khi = lane >> 4;
    int sc2 = (t & 15) * 2;        // X staging: c pair base (0..30)
    int sn4 = (t >> 4) * 4;        // X staging: 4 n rows
    const float* xb = x + (size_t)b * CC * NPIX + n0;
    f32x4 acc[4] = {};
    float ss[4] = {0.f, 0.f, 0.f, 0.f};

    float4 xa, xc;
    // ---- prologue: load + stage c-block 0 into buf 0
    xa = *(const float4*)&xb[(size_t)sc2 * NPIX + sn4];
    xc = *(const float4*)&xb[(size_t)(sc2 + 1) * NPIX + sn4];
    {
        uint* XU = (uint*)Xs[0];
        float va[4] = {xa.x, xa.y, xa.z, xa.w};
        float vc[4] = {xc.x, xc.y, xc.z, xc.w};
#pragma unroll
        for (int j = 0; j < 4; ++j) {
            ss[j] += va[j] * va[j] + vc[j] * vc[j];
            int row = sn4 + j;
            int gp = ((t & 15) >> 2) ^ ((row >> 1) & 3);
            XU[row * 16 + gp * 4 + (t & 3)] = pk2bf(va[j], vc[j]);
        }
    }
    __syncthreads();

    int cur = 0;
    for (int it = 0; it < 16; ++it) {
        bool pre = (it < 15);
        if (pre) {
            int c0 = (it + 1) * 32;
            xa = *(const float4*)&xb[(size_t)(c0 + sc2) * NPIX + sn4];
            xc = *(const float4*)&xb[(size_t)(c0 + sc2 + 1) * NPIX + sn4];
        }
        // ---- MFMA on current buffer; A direct from wb
        {
            const ushort* Xc = Xs[cur];
            int rn = wv * 16 + nlo;
            int gB = khi ^ ((rn >> 1) & 3);
            bf16x8 bfr = *(const bf16x8*)&Xc[rn * 32 + gB * 8];
#pragma unroll
            for (int kf = 0; kf < 4; ++kf) {
                bf16x8 afr = *(const bf16x8*)
                    &wb[(size_t)(kf * 16 + nlo) * CC + it * 32 + khi * 8];
                acc[kf] = MFMA16(afr, bfr, acc[kf], 0, 0, 0);
            }
        }
        if (pre) {
            uint* XU = (uint*)Xs[cur ^ 1];
            float va[4] = {xa.x, xa.y, xa.z, xa.w};
            float vc[4] = {xc.x, xc.y, xc.z, xc.w};
#pragma unroll
            for (int j = 0; j < 4; ++j) {
                ss[j] += va[j] * va[j] + vc[j] * vc[j];
                int row = sn4 + j;
                int gp = ((t & 15) >> 2) ^ ((row >> 1) & 3);
                XU[row * 16 + gp * 4 + (t & 3)] = pk2bf(va[j], vc[j]);
            }
        }
        __syncthreads();
        cur ^= 1;
    }

    // ---- ssq reduce -> invn (LDS only)
#pragma unroll
    for (int j = 0; j < 4; ++j) red[(t & 15) * 64 + sn4 + j] = ss[j];
    __syncthreads();
    if (t < 64) {
        float s = 0.f;
#pragma unroll
        for (int i = 0; i < 16; ++i) s += red[i * 64 + t];
        ivs[t] = 1.f / fmaxf(sqrtf(s), EPSF);
    }
    __syncthreads();

    int nloc = wv * 16 + nlo;
    float invl = ivs[nloc];

    // ---- softmax over k (lane holds 16 k's for one n; combine khi groups)
    float lv[4][4];
    float mm = -1e30f;
#pragma unroll
    for (int kf = 0; kf < 4; ++kf)
#pragma unroll
        for (int r = 0; r < 4; ++r) {
            lv[kf][r] = acc[kf][r] * invl;
            mm = fmaxf(mm, lv[kf][r]);
        }
    mm = fmaxf(mm, __shfl_xor(mm, 16));
    mm = fmaxf(mm, __shfl_xor(mm, 32));
    float ev[4][4], s = 0.f;
#pragma unroll
    for (int kf = 0; kf < 4; ++kf)
#pragma unroll
        for (int r = 0; r < 4; ++r) {
            ev[kf][r] = expf(lv[kf][r] - mm);
            s += ev[kf][r];
        }
    s += __shfl_xor(s, 16);
    s += __shfl_xor(s, 32);
    float sd = 1.f / s;

    // ---- asum partials (unscaled a): reduce over the wave's 16 n
    float av[4][4];
#pragma unroll
    for (int kf = 0; kf < 4; ++kf)
#pragma unroll
        for (int r = 0; r < 4; ++r) av[kf][r] = ev[kf][r] * sd;
#pragma unroll
    for (int off = 1; off < 16; off <<= 1)
#pragma unroll
        for (int kf = 0; kf < 4; ++kf)
#pragma unroll
            for (int r = 0; r < 4; ++r) av[kf][r] += __shfl_xor(av[kf][r], off);
    if (nlo == 0) {
#pragma unroll
        for (int kf = 0; kf < 4; ++kf)
#pragma unroll
            for (int r = 0; r < 4; ++r)
                asw[wv * 64 + kf * 16 + khi * 4 + r] = av[kf][r];
    }

    // ---- a' = a * invn -> a_t[b][k][n] bf16
    ushort* ab = a_t + (size_t)b * KK * NPIX;
#pragma unroll
    for (int kf = 0; kf < 4; ++kf)
#pragma unroll
        for (int r = 0; r < 4; ++r) {
            int k = kf * 16 + khi * 4 + r;
            ab[(size_t)k * NPIX + n0 + nloc] = f2bf(ev[kf][r] * sd * invl);
        }
    __syncthreads();
    if (t < 64) {
        float a4 = asw[t] + asw[64 + t] + asw[128 + t] + asw[192 + t];
        asum_p[((size_t)b * KK + t) * NT + tile] = a4;
    }
}

// ---------------------------------------------------------------------------
// k_vladm (R8-proven): part[s][b][k][c] = sum_{n in chunk} a'[k,n] * x[c,n]
// LDS-free: A-frag = uint4 from a_t[b][k][n] (n-contig);
//           B-frag = 2x float4 from x[b][c][n] (n-contig) + HW cvt.
// ---------------------------------------------------------------------------
__global__ __launch_bounds__(256) void k_vladm(const ushort* __restrict__ a_t,
                                               const float* __restrict__ x,
                                               float* __restrict__ part,
                                               int nchunk) {
    int c0 = blockIdx.x * 64;
    int s  = blockIdx.y;
    int b  = blockIdx.z;
    int t = threadIdx.x, lane = t & 63, wv = t >> 6;
    int clo = lane & 15, nhi = lane >> 4;
    int rc = wv * 16 + clo;                        // this lane's c-column
    const ushort* ab = a_t + (size_t)b * KK * NPIX;
    const float*  xr = x + (size_t)b * CC * NPIX + (size_t)(c0 + rc) * NPIX;
    f32x4 acc[4] = {};
    int nbase = s * nchunk, niters = nchunk / 32;

    for (int it = 0; it < niters; ++it) {
        int nb = nbase + it * 32 + nhi * 8;
        float4 x0 = *(const float4*)&xr[nb];
        float4 x1 = *(const float4*)&xr[nb + 4];
        uint4 bp;
        bp.x = pk2bf(x0.x, x0.y); bp.y = pk2bf(x0.z, x0.w);
        bp.z = pk2bf(x1.x, x1.y); bp.w = pk2bf(x1.z, x1.w);
        bf16x8 bfr = *reinterpret_cast<bf16x8*>(&bp);
#pragma unroll
        for (int kf = 0; kf < 4; ++kf) {
            int rk = kf * 16 + clo;
            bf16x8 afr = *(const bf16x8*)&ab[(size_t)rk * NPIX + nb];
            acc[kf] = MFMA16(afr, bfr, acc[kf], 0, 0, 0);
        }
    }

#pragma unroll
    for (int kf = 0; kf < 4; ++kf)
#pragma unroll
        for (int r = 0; r < 4; ++r) {
            int k = kf * 16 + nhi * 4 + r;
            part[(((size_t)s * BB + b) * KK + k) * CC + c0 + rc] = acc[kf][r];
        }
}

// ---------------------------------------------------------------------------
// k_asum: asum[row] = sum_i asum_p[row][i]   (row = b*KK+k, i < NT)
// ---------------------------------------------------------------------------
__global__ __launch_bounds__(256) void k_asum(const float* __restrict__ asum_p,
                                              float* __restrict__ asum) {
    int row = blockIdx.x * 256 + threadIdx.x;     // 2048 rows exact
    const float* p = asum_p + (size_t)row * NT;
    float s = 0.f;
#pragma unroll
    for (int i = 0; i < NT; ++i) s += p[i];
    asum[row] = s;
}

// ---------------------------------------------------------------------------
// k_intra: sum ns partials, subtract asum*cent, intra-normalize per (b,k),
// accumulate per-b sum of squares.
// ---------------------------------------------------------------------------
__global__ __launch_bounds__(256) void k_intra(const float* __restrict__ part, int ns,
                                               const float* __restrict__ asum,
                                               const float* __restrict__ cent,
                                               float* __restrict__ out,
                                               float* __restrict__ bsum) {
    int row = blockIdx.x;                          // b*KK + k
    int b = row >> 6, k = row & 63;
    int t = threadIdx.x;
    float v0 = 0.f, v1 = 0.f;
    for (int s2 = 0; s2 < ns; ++s2) {
        const float* p = part + (((size_t)s2 * BB + b) * KK + k) * CC;
        v0 += p[t];
        v1 += p[t + 256];
    }
    float as = asum[row];
    v0 -= as * cent[k * CC + t];
    v1 -= as * cent[k * CC + t + 256];
    float ssq = v0 * v0 + v1 * v1;
#pragma unroll
    for (int off = 32; off; off >>= 1) ssq += __shfl_down(ssq, off, 64);
    __shared__ float red[4];
    __shared__ float s_inv;
    if ((t & 63) == 0) red[t >> 6] = ssq;
    __syncthreads();
    if (t == 0) {
        float sm = red[0] + red[1] + red[2] + red[3];
        float inv = 1.f / fmaxf(sqrtf(sm), EPSF);
        s_inv = inv;
        atomicAdd(&bsum[b], sm * inv * inv);
    }
    __syncthreads();
    float inv = s_inv;
    out[(size_t)row * CC + t]       = v0 * inv;
    out[(size_t)row * CC + t + 256] = v1 * inv;
}

// ---------------------------------------------------------------------------
__global__ __launch_bounds__(256) void k_scale(float* __restrict__ out,
                                               const float* __restrict__ bsum) {
    int idx = blockIdx.x * 256 + threadIdx.x;      // B*K*C exact
    int b = idx >> 15;                             // K*C = 32768
    out[idx] *= 1.f / fmaxf(sqrtf(bsum[b]), EPSF);
}

// ---------------------------------------------------------------------------
extern "C" void kernel_launch(void* const* d_in, const int* in_sizes, int n_in,
                              void* d_out, int out_size, void* d_ws, size_t ws_size,
                              hipStream_t stream) {
    const float* x    = (const float*)d_in[0];   // [B,C,H,W]
    const float* cent = (const float*)d_in[1];   // [K,C]
    const float* w    = (const float*)d_in[2];   // [K,C]
    float* out = (float*)d_out;

    char* wsb = (char*)d_ws;
    const size_t oa_at   = 0;                                   // bf16 B*K*N = 6,553,600 B
    const size_t oa_wb   = oa_at + (size_t)BB * KK * NPIX * 2;  // bf16 K*C   =    65,536 B
    const size_t oa_ap   = oa_wb + (size_t)KK * CC * 2;         // f32 2048*NT =  204,800 B
    const size_t oa_as   = oa_ap + (size_t)BB * KK * NT * 4;    // f32 2048   =     8,192 B
    const size_t oa_bsum = oa_as + (size_t)BB * KK * 4;         //                    128 B
    const size_t oa_part = oa_bsum + 128;
    ushort* a_t   = (ushort*)(wsb + oa_at);
    ushort* wb    = (ushort*)(wsb + oa_wb);
    float* asum_p = (float*)(wsb + oa_ap);
    float* asum   = (float*)(wsb + oa_as);
    float* bsum   = (float*)(wsb + oa_bsum);

    // pick ns with nchunk = 1600/ns a multiple of 32: {5, 2, 1}
    const size_t pbytes = (size_t)BB * KK * CC * 4;             // 4 MB per partial
    int ns = 0;
    const int cand[3] = {5, 2, 1};
    for (int i = 0; i < 3; ++i) {
        if (oa_part + (size_t)cand[i] * pbytes <= ws_size) { ns = cand[i]; break; }
    }
    float* part = (ns > 0) ? (float*)(wsb + oa_part) : out;     // ns=1 fallback -> d_out
    if (ns == 0) ns = 1;
    int nchunk = NPIX / ns;

    hipMemsetAsync(bsum, 0, BB * sizeof(float), stream);

    k_wprep <<<dim3((KK * CC / 2) / 256), 256, 0, stream>>>(w, wb);
    k_gemm1m<<<dim3(NT, BB), 256, 0, stream>>>(x, wb, a_t, asum_p);
    k_vladm <<<dim3(CC / 64, ns, BB), 256, 0, stream>>>(a_t, x, part, nchunk);
    k_asum  <<<dim3(BB * KK / 256), 256, 0, stream>>>(asum_p, asum);
    k_intra <<<dim3(BB * KK), 256, 0, stream>>>(part, ns, asum, cent, out, bsum);
    k_scale <<<dim3((BB * KK * CC) / 256), 256, 0, stream>>>(out, bsum);
}

// Round 12
// 104.014 us; speedup vs baseline: 1.2147x; 1.2107x over previous
//
#include <hip/hip_runtime.h>
#include <hip/hip_bf16.h>
#include <math.h>

#define BB   32
#define CC   512
#define NPIX 1600
#define KK   64
#define NT   25        // 64-wide n-tiles in pass A
#define EPSF 1e-12f

typedef __attribute__((ext_vector_type(8))) short bf16x8;
typedef __attribute__((ext_vector_type(4))) float f32x4;
#define MFMA16 __builtin_amdgcn_mfma_f32_16x16x32_bf16

__device__ __forceinline__ ushort f2bf(float f) {
    __hip_bfloat16 h = __float2bfloat16(f);       // RNE, HW cvt
    return *reinterpret_cast<ushort*>(&h);
}
__device__ __forceinline__ uint pk2bf(float a, float b) {
    return (uint)f2bf(a) | ((uint)f2bf(b) << 16);
}

// ---------------------------------------------------------------------------
// k_wprep: w_bf16[k][c] = bf16(w[k][c])   (one-time, 64 KB out, L2-resident)
// ---------------------------------------------------------------------------
__global__ __launch_bounds__(256) void k_wprep(const float* __restrict__ w,
                                               ushort* __restrict__ wb) {
    int i = blockIdx.x * 256 + threadIdx.x;       // over KK*CC/2 = 16384 pairs
    float2 v = *(const float2*)&w[(size_t)i * 2];
    ((uint*)wb)[i] = pk2bf(v.x, v.y);
}

// ---------------------------------------------------------------------------
// k_gemm1m: R7-proven structure (256 thr, dbuf LDS for BOTH operands — MFMA
// never waits on VMEM, so HBM prefetch stays in flight across compute).
// Delta vs R7: W staged from preconverted wb (uint4 copy, no cvt).
// Per (64n tile, b): logits=W@X, ssq->invn, softmax, a'=a*invn -> a_t bf16,
// asum_p.  Granule-XOR swizzle g' = g ^ ((row>>1)&3) on both tiles.
// ---------------------------------------------------------------------------
__global__ __launch_bounds__(256) void k_gemm1m(const float* __restrict__ x,
                                                const ushort* __restrict__ wb,
                                                ushort* __restrict__ a_t,
                                                float* __restrict__ asum_p) {
    int tile = blockIdx.x, b = blockIdx.y;
    int n0 = tile * 64;
    __shared__ __align__(16) ushort Xs[2][64 * 32];   // [n][swz c] bf16
    __shared__ __align__(16) ushort Wsh[2][64 * 32];  // [k][swz c] bf16
    __shared__ __align__(16) float red[16 * 64];
    __shared__ __align__(16) float asw[4 * 64];
    __shared__ __align__(16) float ivs[64];
    int t = threadIdx.x;
    int lane = t & 63, wv = t >> 6;
    int nlo = lane & 15, khi = lane >> 4;
    int sc2 = (t & 15) * 2;        // X staging: c pair base (0..30)
    int sn4 = (t >> 4) * 4;        // X staging: 4 n rows
    int wk  = t >> 2;              // W staging: k row (0..63)
    int wc8 = (t & 3) * 8;         // W staging: c chunk (8 bf16 = uint4)
    const float* xb = x + (size_t)b * CC * NPIX + n0;
    f32x4 acc[4] = {};
    float ss[4] = {0.f, 0.f, 0.f, 0.f};

    float4 xa, xc; uint4 wp;
    // ---- prologue: load + stage c-block 0 into buf 0
    xa = *(const float4*)&xb[(size_t)sc2 * NPIX + sn4];
    xc = *(const float4*)&xb[(size_t)(sc2 + 1) * NPIX + sn4];
    wp = *(const uint4*)&wb[(size_t)wk * CC + wc8];
    {
        uint* XU = (uint*)Xs[0]; uint* WU = (uint*)Wsh[0];
        float va[4] = {xa.x, xa.y, xa.z, xa.w};
        float vc[4] = {xc.x, xc.y, xc.z, xc.w};
#pragma unroll
        for (int j = 0; j < 4; ++j) {
            ss[j] += va[j] * va[j] + vc[j] * vc[j];
            int row = sn4 + j;
            int gp = ((t & 15) >> 2) ^ ((row >> 1) & 3);
            XU[row * 16 + gp * 4 + (t & 3)] = pk2bf(va[j], vc[j]);
        }
        int gp = (t & 3) ^ ((wk >> 1) & 3);
        *(uint4*)&WU[wk * 16 + gp * 4] = wp;
    }
    __syncthreads();

    int cur = 0;
    for (int it = 0; it < 16; ++it) {
        bool pre = (it < 15);
        if (pre) {
            int c0 = (it + 1) * 32;
            xa = *(const float4*)&xb[(size_t)(c0 + sc2) * NPIX + sn4];
            xc = *(const float4*)&xb[(size_t)(c0 + sc2 + 1) * NPIX + sn4];
            wp = *(const uint4*)&wb[(size_t)wk * CC + c0 + wc8];
        }
        // ---- MFMA on current buffer (operands from LDS only)
        {
            const ushort* Xc = Xs[cur];
            const ushort* Wc = Wsh[cur];
            int rn = wv * 16 + nlo;
            int gB = khi ^ ((rn >> 1) & 3);
            bf16x8 bfr = *(const bf16x8*)&Xc[rn * 32 + gB * 8];
#pragma unroll
            for (int kf = 0; kf < 4; ++kf) {
                int rk = kf * 16 + nlo;
                int gA = khi ^ ((rk >> 1) & 3);
                bf16x8 afr = *(const bf16x8*)&Wc[rk * 32 + gA * 8];
                acc[kf] = MFMA16(afr, bfr, acc[kf], 0, 0, 0);
            }
        }
        if (pre) {
            uint* XU = (uint*)Xs[cur ^ 1]; uint* WU = (uint*)Wsh[cur ^ 1];
            float va[4] = {xa.x, xa.y, xa.z, xa.w};
            float vc[4] = {xc.x, xc.y, xc.z, xc.w};
#pragma unroll
            for (int j = 0; j < 4; ++j) {
                ss[j] += va[j] * va[j] + vc[j] * vc[j];
                int row = sn4 + j;
                int gp = ((t & 15) >> 2) ^ ((row >> 1) & 3);
                XU[row * 16 + gp * 4 + (t & 3)] = pk2bf(va[j], vc[j]);
            }
            int gp = (t & 3) ^ ((wk >> 1) & 3);
            *(uint4*)&WU[wk * 16 + gp * 4] = wp;
        }
        __syncthreads();
        cur ^= 1;
    }

    // ---- ssq reduce -> invn (LDS only)
#pragma unroll
    for (int j = 0; j < 4; ++j) red[(t & 15) * 64 + sn4 + j] = ss[j];
    __syncthreads();
    if (t < 64) {
        float s = 0.f;
#pragma unroll
        for (int i = 0; i < 16; ++i) s += red[i * 64 + t];
        ivs[t] = 1.f / fmaxf(sqrtf(s), EPSF);
    }
    __syncthreads();

    int nloc = wv * 16 + nlo;
    float invl = ivs[nloc];

    // ---- softmax over k (lane holds 16 k's for one n; combine khi groups)
    float lv[4][4];
    float mm = -1e30f;
#pragma unroll
    for (int kf = 0; kf < 4; ++kf)
#pragma unroll
        for (int r = 0; r < 4; ++r) {
            lv[kf][r] = acc[kf][r] * invl;
            mm = fmaxf(mm, lv[kf][r]);
        }
    mm = fmaxf(mm, __shfl_xor(mm, 16));
    mm = fmaxf(mm, __shfl_xor(mm, 32));
    float ev[4][4], s = 0.f;
#pragma unroll
    for (int kf = 0; kf < 4; ++kf)
#pragma unroll
        for (int r = 0; r < 4; ++r) {
            ev[kf][r] = expf(lv[kf][r] - mm);
            s += ev[kf][r];
        }
    s += __shfl_xor(s, 16);
    s += __shfl_xor(s, 32);
    float sd = 1.f / s;

    // ---- asum partials (unscaled a): reduce over the wave's 16 n
    float av[4][4];
#pragma unroll
    for (int kf = 0; kf < 4; ++kf)
#pragma unroll
        for (int r = 0; r < 4; ++r) av[kf][r] = ev[kf][r] * sd;
#pragma unroll
    for (int off = 1; off < 16; off <<= 1)
#pragma unroll
        for (int kf = 0; kf < 4; ++kf)
#pragma unroll
            for (int r = 0; r < 4; ++r) av[kf][r] += __shfl_xor(av[kf][r], off);
    if (nlo == 0) {
#pragma unroll
        for (int kf = 0; kf < 4; ++kf)
#pragma unroll
            for (int r = 0; r < 4; ++r)
                asw[wv * 64 + kf * 16 + khi * 4 + r] = av[kf][r];
    }

    // ---- a' = a * invn -> a_t[b][k][n] bf16
    ushort* ab = a_t + (size_t)b * KK * NPIX;
#pragma unroll
    for (int kf = 0; kf < 4; ++kf)
#pragma unroll
        for (int r = 0; r < 4; ++r) {
            int k = kf * 16 + khi * 4 + r;
            ab[(size_t)k * NPIX + n0 + nloc] = f2bf(ev[kf][r] * sd * invl);
        }
    __syncthreads();
    if (t < 64) {
        float a4 = asw[t] + asw[64 + t] + asw[128 + t] + asw[192 + t];
        asum_p[((size_t)b * KK + t) * NT + tile] = a4;
    }
}

// ---------------------------------------------------------------------------
// k_vladm (R8-proven): part[s][b][k][c] = sum_{n in chunk} a'[k,n] * x[c,n]
// LDS-free: all VMEM loads are in-loop operands (no prefetch mixing).
// A-frag = uint4 from a_t[b][k][n]; B-frag = 2x float4 from x + HW cvt.
// ---------------------------------------------------------------------------
__global__ __launch_bounds__(256) void k_vladm(const ushort* __restrict__ a_t,
                                               const float* __restrict__ x,
                                               float* __restrict__ part,
                                               int nchunk) {
    int c0 = blockIdx.x * 64;
    int s  = blockIdx.y;
    int b  = blockIdx.z;
    int t = threadIdx.x, lane = t & 63, wv = t >> 6;
    int clo = lane & 15, nhi = lane >> 4;
    int rc = wv * 16 + clo;                        // this lane's c-column
    const ushort* ab = a_t + (size_t)b * KK * NPIX;
    const float*  xr = x + (size_t)b * CC * NPIX + (size_t)(c0 + rc) * NPIX;
    f32x4 acc[4] = {};
    int nbase = s * nchunk, niters = nchunk / 32;

    for (int it = 0; it < niters; ++it) {
        int nb = nbase + it * 32 + nhi * 8;
        float4 x0 = *(const float4*)&xr[nb];
        float4 x1 = *(const float4*)&xr[nb + 4];
        uint4 bp;
        bp.x = pk2bf(x0.x, x0.y); bp.y = pk2bf(x0.z, x0.w);
        bp.z = pk2bf(x1.x, x1.y); bp.w = pk2bf(x1.z, x1.w);
        bf16x8 bfr = *reinterpret_cast<bf16x8*>(&bp);
#pragma unroll
        for (int kf = 0; kf < 4; ++kf) {
            int rk = kf * 16 + clo;
            bf16x8 afr = *(const bf16x8*)&ab[(size_t)rk * NPIX + nb];
            acc[kf] = MFMA16(afr, bfr, acc[kf], 0, 0, 0);
        }
    }

#pragma unroll
    for (int kf = 0; kf < 4; ++kf)
#pragma unroll
        for (int r = 0; r < 4; ++r) {
            int k = kf * 16 + nhi * 4 + r;
            part[(((size_t)s * BB + b) * KK + k) * CC + c0 + rc] = acc[kf][r];
        }
}

// ---------------------------------------------------------------------------
// k_asum: asum[row] = sum_i asum_p[row][i]   (row = b*KK+k, i < NT)
// ---------------------------------------------------------------------------
__global__ __launch_bounds__(256) void k_asum(const float* __restrict__ asum_p,
                                              float* __restrict__ asum) {
    int row = blockIdx.x * 256 + threadIdx.x;     // 2048 rows exact
    const float* p = asum_p + (size_t)row * NT;
    float s = 0.f;
#pragma unroll
    for (int i = 0; i < NT; ++i) s += p[i];
    asum[row] = s;
}

// ---------------------------------------------------------------------------
// k_intra: sum ns partials, subtract asum*cent, intra-normalize per (b,k),
// accumulate per-b sum of squares.
// ---------------------------------------------------------------------------
__global__ __launch_bounds__(256) void k_intra(const float* __restrict__ part, int ns,
                                               const float* __restrict__ asum,
                                               const float* __restrict__ cent,
                                               float* __restrict__ out,
                                               float* __restrict__ bsum) {
    int row = blockIdx.x;                          // b*KK + k
    int b = row >> 6, k = row & 63;
    int t = threadIdx.x;
    float v0 = 0.f, v1 = 0.f;
    for (int s2 = 0; s2 < ns; ++s2) {
        const float* p = part + (((size_t)s2 * BB + b) * KK + k) * CC;
        v0 += p[t];
        v1 += p[t + 256];
    }
    float as = asum[row];
    v0 -= as * cent[k * CC + t];
    v1 -= as * cent[k * CC + t + 256];
    float ssq = v0 * v0 + v1 * v1;
#pragma unroll
    for (int off = 32; off; off >>= 1) ssq += __shfl_down(ssq, off, 64);
    __shared__ float red[4];
    __shared__ float s_inv;
    if ((t & 63) == 0) red[t >> 6] = ssq;
    __syncthreads();
    if (t == 0) {
        float sm = red[0] + red[1] + red[2] + red[3];
        float inv = 1.f / fmaxf(sqrtf(sm), EPSF);
        s_inv = inv;
        atomicAdd(&bsum[b], sm * inv * inv);
    }
    __syncthreads();
    float inv = s_inv;
    out[(size_t)row * CC + t]       = v0 * inv;
    out[(size_t)row * CC + t + 256] = v1 * inv;
}

// ---------------------------------------------------------------------------
__global__ __launch_bounds__(256) void k_scale(float* __restrict__ out,
                                               const float* __restrict__ bsum) {
    int idx = blockIdx.x * 256 + threadIdx.x;      // B*K*C exact
    int b = idx >> 15;                             // K*C = 32768
    out[idx] *= 1.f / fmaxf(sqrtf(bsum[b]), EPSF);
}

// ---------------------------------------------------------------------------
extern "C" void kernel_launch(void* const* d_in, const int* in_sizes, int n_in,
                              void* d_out, int out_size, void* d_ws, size_t ws_size,
                              hipStream_t stream) {
    const float* x    = (const float*)d_in[0];   // [B,C,H,W]
    const float* cent = (const float*)d_in[1];   // [K,C]
    const float* w    = (const float*)d_in[2];   // [K,C]
    float* out = (float*)d_out;

    char* wsb = (char*)d_ws;
    const size_t oa_at   = 0;                                   // bf16 B*K*N = 6,553,600 B
    const size_t oa_wb   = oa_at + (size_t)BB * KK * NPIX * 2;  // bf16 K*C   =    65,536 B
    const size_t oa_ap   = oa_wb + (size_t)KK * CC * 2;         // f32 2048*NT =  204,800 B
    const size_t oa_as   = oa_ap + (size_t)BB * KK * NT * 4;    // f32 2048   =     8,192 B
    const size_t oa_bsum = oa_as + (size_t)BB * KK * 4;         //                    128 B
    const size_t oa_part = oa_bsum + 128;
    ushort* a_t   = (ushort*)(wsb + oa_at);
    ushort* wb    = (ushort*)(wsb + oa_wb);
    float* asum_p = (float*)(wsb + oa_ap);
    float* asum   = (float*)(wsb + oa_as);
    float* bsum   = (float*)(wsb + oa_bsum);

    // pick ns with nchunk = 1600/ns a multiple of 32: {5, 2, 1}
    const size_t pbytes = (size_t)BB * KK * CC * 4;             // 4 MB per partial
    int ns = 0;
    const int cand[3] = {5, 2, 1};
    for (int i = 0; i < 3; ++i) {
        if (oa_part + (size_t)cand[i] * pbytes <= ws_size) { ns = cand[i]; break; }
    }
    float* part = (ns > 0) ? (float*)(wsb + oa_part) : out;     // ns=1 fallback -> d_out
    if (ns == 0) ns = 1;
    int nchunk = NPIX / ns;

    hipMemsetAsync(bsum, 0, BB * sizeof(float), stream);

    k_wprep <<<dim3((KK * CC / 2) / 256), 256, 0, stream>>>(w, wb);
    k_gemm1m<<<dim3(NT, BB), 256, 0, stream>>>(x, wb, a_t, asum_p);
    k_vladm <<<dim3(CC / 64, ns, BB), 256, 0, stream>>>(a_t, x, part, nchunk);
    k_asum  <<<dim3(BB * KK / 256), 256, 0, stream>>>(asum_p, asum);
    k_intra <<<dim3(BB * KK), 256, 0, stream>>>(part, ns, asum, cent, out, bsum);
    k_scale <<<dim3((BB * KK * CC) / 256), 256, 0, stream>>>(out, bsum);
}

// Round 13
// 93.474 us; speedup vs baseline: 1.3517x; 1.1128x over previous
//
#include <hip/hip_runtime.h>
#include <hip/hip_bf16.h>
#include <math.h>

#define BB   32
#define CC   512
#define NPIX 1600
#define KK   64
#define NT   25        // 64-wide n-tiles in pass A
#define EPSF 1e-12f

typedef __attribute__((ext_vector_type(8))) short bf16x8;
typedef __attribute__((ext_vector_type(4))) float f32x4;
#define MFMA16 __builtin_amdgcn_mfma_f32_16x16x32_bf16

__device__ __forceinline__ ushort f2bf(float f) {
    __hip_bfloat16 h = __float2bfloat16(f);       // RNE, HW cvt
    return *reinterpret_cast<ushort*>(&h);
}
__device__ __forceinline__ uint pk2bf(float a, float b) {
    return (uint)f2bf(a) | ((uint)f2bf(b) << 16);
}

// ---------------------------------------------------------------------------
// k_wprep: w_bf16[k][c] = bf16(w[k][c])   (one-time, 64 KB out, L2-resident)
// ---------------------------------------------------------------------------
__global__ __launch_bounds__(256) void k_wprep(const float* __restrict__ w,
                                               ushort* __restrict__ wb) {
    int i = blockIdx.x * 256 + threadIdx.x;       // over KK*CC/2 = 16384 pairs
    float2 v = *(const float2*)&w[(size_t)i * 2];
    ((uint*)wb)[i] = pk2bf(v.x, v.y);
}

// ---------------------------------------------------------------------------
// k_gemm1m (R12-tested): 256 thr, dbuf LDS for BOTH operands — MFMA operands
// come from LDS only, so the HBM prefetch queue never blocks compute.
// W staged from preconverted wb (uint4 copy).  Granule-XOR swizzle
// g' = g ^ ((row>>1)&3) on both tiles.
// ---------------------------------------------------------------------------
__global__ __launch_bounds__(256) void k_gemm1m(const float* __restrict__ x,
                                                const ushort* __restrict__ wb,
                                                ushort* __restrict__ a_t,
                                                float* __restrict__ asum_p) {
    int tile = blockIdx.x, b = blockIdx.y;
    int n0 = tile * 64;
    __shared__ __align__(16) ushort Xs[2][64 * 32];   // [n][swz c] bf16
    __shared__ __align__(16) ushort Wsh[2][64 * 32];  // [k][swz c] bf16
    __shared__ __align__(16) float red[16 * 64];
    __shared__ __align__(16) float asw[4 * 64];
    __shared__ __align__(16) float ivs[64];
    int t = threadIdx.x;
    int lane = t & 63, wv = t >> 6;
    int nlo = lane & 15, khi = lane >> 4;
    int sc2 = (t & 15) * 2;        // X staging: c pair base (0..30)
    int sn4 = (t >> 4) * 4;        // X staging: 4 n rows
    int wk  = t >> 2;              // W staging: k row (0..63)
    int wc8 = (t & 3) * 8;         // W staging: c chunk (8 bf16 = uint4)
    const float* xb = x + (size_t)b * CC * NPIX + n0;
    f32x4 acc[4] = {};
    float ss[4] = {0.f, 0.f, 0.f, 0.f};

    float4 xa, xc; uint4 wp;
    // ---- prologue: load + stage c-block 0 into buf 0
    xa = *(const float4*)&xb[(size_t)sc2 * NPIX + sn4];
    xc = *(const float4*)&xb[(size_t)(sc2 + 1) * NPIX + sn4];
    wp = *(const uint4*)&wb[(size_t)wk * CC + wc8];
    {
        uint* XU = (uint*)Xs[0]; uint* WU = (uint*)Wsh[0];
        float va[4] = {xa.x, xa.y, xa.z, xa.w};
        float vc[4] = {xc.x, xc.y, xc.z, xc.w};
#pragma unroll
        for (int j = 0; j < 4; ++j) {
            ss[j] += va[j] * va[j] + vc[j] * vc[j];
            int row = sn4 + j;
            int gp = ((t & 15) >> 2) ^ ((row >> 1) & 3);
            XU[row * 16 + gp * 4 + (t & 3)] = pk2bf(va[j], vc[j]);
        }
        int gp = (t & 3) ^ ((wk >> 1) & 3);
        *(uint4*)&WU[wk * 16 + gp * 4] = wp;
    }
    __syncthreads();

    int cur = 0;
    for (int it = 0; it < 16; ++it) {
        bool pre = (it < 15);
        if (pre) {
            int c0 = (it + 1) * 32;
            xa = *(const float4*)&xb[(size_t)(c0 + sc2) * NPIX + sn4];
            xc = *(const float4*)&xb[(size_t)(c0 + sc2 + 1) * NPIX + sn4];
            wp = *(const uint4*)&wb[(size_t)wk * CC + c0 + wc8];
        }
        // ---- MFMA on current buffer (operands from LDS only)
        {
            const ushort* Xc = Xs[cur];
            const ushort* Wc = Wsh[cur];
            int rn = wv * 16 + nlo;
            int gB = khi ^ ((rn >> 1) & 3);
            bf16x8 bfr = *(const bf16x8*)&Xc[rn * 32 + gB * 8];
#pragma unroll
            for (int kf = 0; kf < 4; ++kf) {
                int rk = kf * 16 + nlo;
                int gA = khi ^ ((rk >> 1) & 3);
                bf16x8 afr = *(const bf16x8*)&Wc[rk * 32 + gA * 8];
                acc[kf] = MFMA16(afr, bfr, acc[kf], 0, 0, 0);
            }
        }
        if (pre) {
            uint* XU = (uint*)Xs[cur ^ 1]; uint* WU = (uint*)Wsh[cur ^ 1];
            float va[4] = {xa.x, xa.y, xa.z, xa.w};
            float vc[4] = {xc.x, xc.y, xc.z, xc.w};
#pragma unroll
            for (int j = 0; j < 4; ++j) {
                ss[j] += va[j] * va[j] + vc[j] * vc[j];
                int row = sn4 + j;
                int gp = ((t & 15) >> 2) ^ ((row >> 1) & 3);
                XU[row * 16 + gp * 4 + (t & 3)] = pk2bf(va[j], vc[j]);
            }
            int gp = (t & 3) ^ ((wk >> 1) & 3);
            *(uint4*)&WU[wk * 16 + gp * 4] = wp;
        }
        __syncthreads();
        cur ^= 1;
    }

    // ---- ssq reduce -> invn (LDS only)
#pragma unroll
    for (int j = 0; j < 4; ++j) red[(t & 15) * 64 + sn4 + j] = ss[j];
    __syncthreads();
    if (t < 64) {
        float s = 0.f;
#pragma unroll
        for (int i = 0; i < 16; ++i) s += red[i * 64 + t];
        ivs[t] = 1.f / fmaxf(sqrtf(s), EPSF);
    }
    __syncthreads();

    int nloc = wv * 16 + nlo;
    float invl = ivs[nloc];

    // ---- softmax over k (lane holds 16 k's for one n; combine khi groups)
    float lv[4][4];
    float mm = -1e30f;
#pragma unroll
    for (int kf = 0; kf < 4; ++kf)
#pragma unroll
        for (int r = 0; r < 4; ++r) {
            lv[kf][r] = acc[kf][r] * invl;
            mm = fmaxf(mm, lv[kf][r]);
        }
    mm = fmaxf(mm, __shfl_xor(mm, 16));
    mm = fmaxf(mm, __shfl_xor(mm, 32));
    float ev[4][4], s = 0.f;
#pragma unroll
    for (int kf = 0; kf < 4; ++kf)
#pragma unroll
        for (int r = 0; r < 4; ++r) {
            ev[kf][r] = expf(lv[kf][r] - mm);
            s += ev[kf][r];
        }
    s += __shfl_xor(s, 16);
    s += __shfl_xor(s, 32);
    float sd = 1.f / s;

    // ---- asum partials (unscaled a): reduce over the wave's 16 n
    float av[4][4];
#pragma unroll
    for (int kf = 0; kf < 4; ++kf)
#pragma unroll
        for (int r = 0; r < 4; ++r) av[kf][r] = ev[kf][r] * sd;
#pragma unroll
    for (int off = 1; off < 16; off <<= 1)
#pragma unroll
        for (int kf = 0; kf < 4; ++kf)
#pragma unroll
            for (int r = 0; r < 4; ++r) av[kf][r] += __shfl_xor(av[kf][r], off);
    if (nlo == 0) {
#pragma unroll
        for (int kf = 0; kf < 4; ++kf)
#pragma unroll
            for (int r = 0; r < 4; ++r)
                asw[wv * 64 + kf * 16 + khi * 4 + r] = av[kf][r];
    }

    // ---- a' = a * invn -> a_t[b][k][n] bf16
    ushort* ab = a_t + (size_t)b * KK * NPIX;
#pragma unroll
    for (int kf = 0; kf < 4; ++kf)
#pragma unroll
        for (int r = 0; r < 4; ++r) {
            int k = kf * 16 + khi * 4 + r;
            ab[(size_t)k * NPIX + n0 + nloc] = f2bf(ev[kf][r] * sd * invl);
        }
    __syncthreads();
    if (t < 64) {
        float a4 = asw[t] + asw[64 + t] + asw[128 + t] + asw[192 + t];
        asum_p[((size_t)b * KK + t) * NT + tile] = a4;
    }
}

// ---------------------------------------------------------------------------
// k_vladm (round-7-proven LDS-staged version): part[s][b][k][c] =
// sum_{n in chunk} a'[k,n] * x[c,n]   (MFMA, D[k-rows][c-cols])
// A-frag: a_t tile [64k][32n] bf16, staged via linear coalesced uint4.
// B-frag: x tile [64c][32n] bf16, staged via float4 + HW cvt (rows linear).
// Granule-XOR swizzle, double-buffered, 1 barrier/step.
// ---------------------------------------------------------------------------
__global__ __launch_bounds__(256) void k_vladm(const ushort* __restrict__ a_t,
                                               const float* __restrict__ x,
                                               float* __restrict__ part,
                                               int nchunk) {
    int c0 = blockIdx.x * 64;
    int s  = blockIdx.y;
    int b  = blockIdx.z;
    __shared__ __align__(16) ushort Ash[2][64 * 32];  // [k][swz n]
    __shared__ __align__(16) ushort Xsh[2][64 * 32];  // [c][swz n]
    int t = threadIdx.x;
    int lane = t & 63, wv = t >> 6;
    int sk  = t >> 2;              // staging row (k for A, c for X)
    int sn8 = (t & 3) * 8;         // staging n chunk
    const ushort* ab = a_t + (size_t)b * KK * NPIX;
    const float*  xb = x + (size_t)b * CC * NPIX;
    f32x4 acc[4] = {};
    int nbase = s * nchunk;
    int niters = nchunk / 32;

    uint4 ar; float4 x0, x1;
    // ---- prologue
    ar = *(const uint4*)&ab[(size_t)sk * NPIX + nbase + sn8];
    x0 = *(const float4*)&xb[(size_t)(c0 + sk) * NPIX + nbase + sn8];
    x1 = *(const float4*)&xb[(size_t)(c0 + sk) * NPIX + nbase + sn8 + 4];
    {
        uint* AU = (uint*)Ash[0]; uint* XU = (uint*)Xsh[0];
        int gp = (t & 3) ^ ((sk >> 1) & 3);
        *(uint4*)&AU[sk * 16 + gp * 4] = ar;
        uint4 xp;
        xp.x = pk2bf(x0.x, x0.y); xp.y = pk2bf(x0.z, x0.w);
        xp.z = pk2bf(x1.x, x1.y); xp.w = pk2bf(x1.z, x1.w);
        *(uint4*)&XU[sk * 16 + gp * 4] = xp;
    }
    __syncthreads();

    int cur = 0;
    for (int it = 0; it < niters; ++it) {
        bool pre = (it + 1 < niters);
        if (pre) {
            int ng = nbase + (it + 1) * 32;
            ar = *(const uint4*)&ab[(size_t)sk * NPIX + ng + sn8];
            x0 = *(const float4*)&xb[(size_t)(c0 + sk) * NPIX + ng + sn8];
            x1 = *(const float4*)&xb[(size_t)(c0 + sk) * NPIX + ng + sn8 + 4];
        }
        {
            const ushort* Ac = Ash[cur];
            const ushort* Xc = Xsh[cur];
            int rc = wv * 16 + (lane & 15);
            int gB = (lane >> 4) ^ ((rc >> 1) & 3);
            bf16x8 bfr = *(const bf16x8*)&Xc[rc * 32 + gB * 8];
#pragma unroll
            for (int kf = 0; kf < 4; ++kf) {
                int rk = kf * 16 + (lane & 15);
                int gA = (lane >> 4) ^ ((rk >> 1) & 3);
                bf16x8 afr = *(const bf16x8*)&Ac[rk * 32 + gA * 8];
                acc[kf] = MFMA16(afr, bfr, acc[kf], 0, 0, 0);
            }
        }
        if (pre) {
            uint* AU = (uint*)Ash[cur ^ 1]; uint* XU = (uint*)Xsh[cur ^ 1];
            int gp = (t & 3) ^ ((sk >> 1) & 3);
            *(uint4*)&AU[sk * 16 + gp * 4] = ar;
            uint4 xp;
            xp.x = pk2bf(x0.x, x0.y); xp.y = pk2bf(x0.z, x0.w);
            xp.z = pk2bf(x1.x, x1.y); xp.w = pk2bf(x1.z, x1.w);
            *(uint4*)&XU[sk * 16 + gp * 4] = xp;
        }
        __syncthreads();
        cur ^= 1;
    }

    // ---- epilogue: D[k][c] -> part[s][b][k][c]
#pragma unroll
    for (int kf = 0; kf < 4; ++kf)
#pragma unroll
        for (int r = 0; r < 4; ++r) {
            int k = kf * 16 + (lane >> 4) * 4 + r;
            int c = c0 + wv * 16 + (lane & 15);
            part[(((size_t)s * BB + b) * KK + k) * CC + c] = acc[kf][r];
        }
}

// ---------------------------------------------------------------------------
// k_asum: asum[row] = sum_i asum_p[row][i]   (row = b*KK+k, i < NT)
// ---------------------------------------------------------------------------
__global__ __launch_bounds__(256) void k_asum(const float* __restrict__ asum_p,
                                              float* __restrict__ asum) {
    int row = blockIdx.x * 256 + threadIdx.x;     // 2048 rows exact
    const float* p = asum_p + (size_t)row * NT;
    float s = 0.f;
#pragma unroll
    for (int i = 0; i < NT; ++i) s += p[i];
    asum[row] = s;
}

// ---------------------------------------------------------------------------
// k_intra: sum ns partials, subtract asum*cent, intra-normalize per (b,k),
// accumulate per-b sum of squares.
// ---------------------------------------------------------------------------
__global__ __launch_bounds__(256) void k_intra(const float* __restrict__ part, int ns,
                                               const float* __restrict__ asum,
                                               const float* __restrict__ cent,
                                               float* __restrict__ out,
                                               float* __restrict__ bsum) {
    int row = blockIdx.x;                          // b*KK + k
    int b = row >> 6, k = row & 63;
    int t = threadIdx.x;
    float v0 = 0.f, v1 = 0.f;
    for (int s2 = 0; s2 < ns; ++s2) {
        const float* p = part + (((size_t)s2 * BB + b) * KK + k) * CC;
        v0 += p[t];
        v1 += p[t + 256];
    }
    float as = asum[row];
    v0 -= as * cent[k * CC + t];
    v1 -= as * cent[k * CC + t + 256];
    float ssq = v0 * v0 + v1 * v1;
#pragma unroll
    for (int off = 32; off; off >>= 1) ssq += __shfl_down(ssq, off, 64);
    __shared__ float red[4];
    __shared__ float s_inv;
    if ((t & 63) == 0) red[t >> 6] = ssq;
    __syncthreads();
    if (t == 0) {
        float sm = red[0] + red[1] + red[2] + red[3];
        float inv = 1.f / fmaxf(sqrtf(sm), EPSF);
        s_inv = inv;
        atomicAdd(&bsum[b], sm * inv * inv);
    }
    __syncthreads();
    float inv = s_inv;
    out[(size_t)row * CC + t]       = v0 * inv;
    out[(size_t)row * CC + t + 256] = v1 * inv;
}

// ---------------------------------------------------------------------------
__global__ __launch_bounds__(256) void k_scale(float* __restrict__ out,
                                               const float* __restrict__ bsum) {
    int idx = blockIdx.x * 256 + threadIdx.x;      // B*K*C exact
    int b = idx >> 15;                             // K*C = 32768
    out[idx] *= 1.f / fmaxf(sqrtf(bsum[b]), EPSF);
}

// ---------------------------------------------------------------------------
extern "C" void kernel_launch(void* const* d_in, const int* in_sizes, int n_in,
                              void* d_out, int out_size, void* d_ws, size_t ws_size,
                              hipStream_t stream) {
    const float* x    = (const float*)d_in[0];   // [B,C,H,W]
    const float* cent = (const float*)d_in[1];   // [K,C]
    const float* w    = (const float*)d_in[2];   // [K,C]
    float* out = (float*)d_out;

    char* wsb = (char*)d_ws;
    const size_t oa_at   = 0;                                   // bf16 B*K*N = 6,553,600 B
    const size_t oa_wb   = oa_at + (size_t)BB * KK * NPIX * 2;  // bf16 K*C   =    65,536 B
    const size_t oa_ap   = oa_wb + (size_t)KK * CC * 2;         // f32 2048*NT =  204,800 B
    const size_t oa_as   = oa_ap + (size_t)BB * KK * NT * 4;    // f32 2048   =     8,192 B
    const size_t oa_bsum = oa_as + (size_t)BB * KK * 4;         //                    128 B
    const size_t oa_part = oa_bsum + 128;
    ushort* a_t   = (ushort*)(wsb + oa_at);
    ushort* wb    = (ushort*)(wsb + oa_wb);
    float* asum_p = (float*)(wsb + oa_ap);
    float* asum   = (float*)(wsb + oa_as);
    float* bsum   = (float*)(wsb + oa_bsum);

    // pick ns with nchunk = 1600/ns a multiple of 32: {5, 2, 1}
    const size_t pbytes = (size_t)BB * KK * CC * 4;             // 4 MB per partial
    int ns = 0;
    const int cand[3] = {5, 2, 1};
    for (int i = 0; i < 3; ++i) {
        if (oa_part + (size_t)cand[i] * pbytes <= ws_size) { ns = cand[i]; break; }
    }
    float* part = (ns > 0) ? (float*)(wsb + oa_part) : out;     // ns=1 fallback -> d_out
    if (ns == 0) ns = 1;
    int nchunk = NPIX / ns;

    hipMemsetAsync(bsum, 0, BB * sizeof(float), stream);

    k_wprep <<<dim3((KK * CC / 2) / 256), 256, 0, stream>>>(w, wb);
    k_gemm1m<<<dim3(NT, BB), 256, 0, stream>>>(x, wb, a_t, asum_p);
    k_vladm <<<dim3(CC / 64, ns, BB), 256, 0, stream>>>(a_t, x, part, nchunk);
    k_asum  <<<dim3(BB * KK / 256), 256, 0, stream>>>(asum_p, asum);
    k_intra <<<dim3(BB * KK), 256, 0, stream>>>(part, ns, asum, cent, out, bsum);
    k_scale <<<dim3((BB * KK * CC) / 256), 256, 0, stream>>>(out, bsum);
}

// Round 14
// 89.298 us; speedup vs baseline: 1.4149x; 1.0468x over previous
//
#include <hip/hip_runtime.h>
#include <hip/hip_bf16.h>
#include <math.h>

#define BB   32
#define CC   512
#define NPIX 1600
#define KK   64
#define NT   25        // 64-wide n-tiles in pass A
#define EPSF 1e-12f

typedef __attribute__((ext_vector_type(8))) short bf16x8;
typedef __attribute__((ext_vector_type(4))) float f32x4;
#define MFMA16 __builtin_amdgcn_mfma_f32_16x16x32_bf16

__device__ __forceinline__ ushort f2bf(float f) {
    __hip_bfloat16 h = __float2bfloat16(f);       // RNE, HW cvt
    return *reinterpret_cast<ushort*>(&h);
}
__device__ __forceinline__ uint pk2bf(float a, float b) {
    return (uint)f2bf(a) | ((uint)f2bf(b) << 16);
}

// ---------------------------------------------------------------------------
// k_gemm1m: R7/R13-proven 256-thr dbuf-LDS structure + 2-deep prefetch:
//   it: LOAD(it+2)->regs | COMPUTE(it) from LDS | STORE(it+1)->LDS | barrier
// Doubles per-wave outstanding staging loads (wave count is pinned at
// 12.5/CU by the decomposition, so latency tolerance must come per-wave).
// MFMA operands from LDS only (vmcnt-mixing lesson, R11/R12).
// W cvt in-kernel (R7-proven; no wprep pass).
// ---------------------------------------------------------------------------
__global__ __launch_bounds__(256) void k_gemm1m(const float* __restrict__ x,
                                                const float* __restrict__ w,
                                                ushort* __restrict__ a_t,
                                                float* __restrict__ asum_p) {
    int tile = blockIdx.x, b = blockIdx.y;
    int n0 = tile * 64;
    __shared__ __align__(16) ushort Xs[2][64 * 32];   // [n][swz c] bf16
    __shared__ __align__(16) ushort Wsh[2][64 * 32];  // [k][swz c] bf16
    __shared__ __align__(16) float red[16 * 64];
    __shared__ __align__(16) float asw[4 * 64];
    __shared__ __align__(16) float ivs[64];
    int t = threadIdx.x;
    int lane = t & 63, wv = t >> 6;
    int nlo = lane & 15, khi = lane >> 4;
    int sc2 = (t & 15) * 2;        // X staging: c pair base (0..30)
    int sn4 = (t >> 4) * 4;        // X staging: 4 n rows
    int wk  = t >> 2;              // W staging: k row (0..63)
    int wc8 = (t & 3) * 8;         // W staging: c chunk (8 floats)
    const float* xb = x + (size_t)b * CC * NPIX + n0;
    f32x4 acc[4] = {};
    float ss[4] = {0.f, 0.f, 0.f, 0.f};

    float4 xa[2], xc[2], wa[2], wc2[2];            // 2-deep prefetch slots

#define LOADQ(it_, sl_)                                                      \
    {                                                                        \
        int cb_ = (it_) * 32;                                                \
        xa[sl_]  = *(const float4*)&xb[(size_t)(cb_ + sc2) * NPIX + sn4];    \
        xc[sl_]  = *(const float4*)&xb[(size_t)(cb_ + sc2 + 1) * NPIX + sn4];\
        wa[sl_]  = *(const float4*)&w[(size_t)wk * CC + cb_ + wc8];          \
        wc2[sl_] = *(const float4*)&w[(size_t)wk * CC + cb_ + wc8 + 4];      \
    }
#define STOREQ(it_, sl_)                                                     \
    {                                                                        \
        uint* XU = (uint*)Xs[(it_) & 1];                                     \
        uint* WU = (uint*)Wsh[(it_) & 1];                                    \
        float va_[4] = {xa[sl_].x, xa[sl_].y, xa[sl_].z, xa[sl_].w};         \
        float vc_[4] = {xc[sl_].x, xc[sl_].y, xc[sl_].z, xc[sl_].w};         \
        _Pragma("unroll")                                                    \
        for (int j = 0; j < 4; ++j) {                                        \
            ss[j] += va_[j] * va_[j] + vc_[j] * vc_[j];                      \
            int row_ = sn4 + j;                                              \
            int gp_ = ((t & 15) >> 2) ^ ((row_ >> 1) & 3);                   \
            XU[row_ * 16 + gp_ * 4 + (t & 3)] = pk2bf(va_[j], vc_[j]);       \
        }                                                                    \
        uint4 wp_;                                                           \
        wp_.x = pk2bf(wa[sl_].x,  wa[sl_].y);                                \
        wp_.y = pk2bf(wa[sl_].z,  wa[sl_].w);                                \
        wp_.z = pk2bf(wc2[sl_].x, wc2[sl_].y);                               \
        wp_.w = pk2bf(wc2[sl_].z, wc2[sl_].w);                               \
        int gw_ = (t & 3) ^ ((wk >> 1) & 3);                                 \
        *(uint4*)&WU[wk * 16 + gw_ * 4] = wp_;                               \
    }

    // ---- prologue: loads for steps 0,1; stage step 0
    LOADQ(0, 0);
    LOADQ(1, 1);
    STOREQ(0, 0);
    __syncthreads();

#pragma unroll
    for (int it = 0; it < 16; ++it) {
        if (it + 2 < 16) LOADQ(it + 2, it & 1);
        // ---- MFMA on current buffer (operands from LDS only)
        {
            const ushort* Xc = Xs[it & 1];
            const ushort* Wc = Wsh[it & 1];
            int rn = wv * 16 + nlo;
            int gB = khi ^ ((rn >> 1) & 3);
            bf16x8 bfr = *(const bf16x8*)&Xc[rn * 32 + gB * 8];
#pragma unroll
            for (int kf = 0; kf < 4; ++kf) {
                int rk = kf * 16 + nlo;
                int gA = khi ^ ((rk >> 1) & 3);
                bf16x8 afr = *(const bf16x8*)&Wc[rk * 32 + gA * 8];
                acc[kf] = MFMA16(afr, bfr, acc[kf], 0, 0, 0);
            }
        }
        if (it + 1 < 16) STOREQ(it + 1, (it + 1) & 1);
        __syncthreads();
    }
#undef LOADQ
#undef STOREQ

    // ---- ssq reduce -> invn (LDS only)
#pragma unroll
    for (int j = 0; j < 4; ++j) red[(t & 15) * 64 + sn4 + j] = ss[j];
    __syncthreads();
    if (t < 64) {
        float s = 0.f;
#pragma unroll
        for (int i = 0; i < 16; ++i) s += red[i * 64 + t];
        ivs[t] = 1.f / fmaxf(sqrtf(s), EPSF);
    }
    __syncthreads();

    int nloc = wv * 16 + nlo;
    float invl = ivs[nloc];

    // ---- softmax over k (lane holds 16 k's for one n; combine khi groups)
    float lv[4][4];
    float mm = -1e30f;
#pragma unroll
    for (int kf = 0; kf < 4; ++kf)
#pragma unroll
        for (int r = 0; r < 4; ++r) {
            lv[kf][r] = acc[kf][r] * invl;
            mm = fmaxf(mm, lv[kf][r]);
        }
    mm = fmaxf(mm, __shfl_xor(mm, 16));
    mm = fmaxf(mm, __shfl_xor(mm, 32));
    float ev[4][4], s = 0.f;
#pragma unroll
    for (int kf = 0; kf < 4; ++kf)
#pragma unroll
        for (int r = 0; r < 4; ++r) {
            ev[kf][r] = expf(lv[kf][r] - mm);
            s += ev[kf][r];
        }
    s += __shfl_xor(s, 16);
    s += __shfl_xor(s, 32);
    float sd = 1.f / s;

    // ---- asum partials (unscaled a): reduce over the wave's 16 n
    float av[4][4];
#pragma unroll
    for (int kf = 0; kf < 4; ++kf)
#pragma unroll
        for (int r = 0; r < 4; ++r) av[kf][r] = ev[kf][r] * sd;
#pragma unroll
    for (int off = 1; off < 16; off <<= 1)
#pragma unroll
        for (int kf = 0; kf < 4; ++kf)
#pragma unroll
            for (int r = 0; r < 4; ++r) av[kf][r] += __shfl_xor(av[kf][r], off);
    if (nlo == 0) {
#pragma unroll
        for (int kf = 0; kf < 4; ++kf)
#pragma unroll
            for (int r = 0; r < 4; ++r)
                asw[wv * 64 + kf * 16 + khi * 4 + r] = av[kf][r];
    }

    // ---- a' = a * invn -> a_t[b][k][n] bf16
    ushort* ab = a_t + (size_t)b * KK * NPIX;
#pragma unroll
    for (int kf = 0; kf < 4; ++kf)
#pragma unroll
        for (int r = 0; r < 4; ++r) {
            int k = kf * 16 + khi * 4 + r;
            ab[(size_t)k * NPIX + n0 + nloc] = f2bf(ev[kf][r] * sd * invl);
        }
    __syncthreads();
    if (t < 64) {
        float a4 = asw[t] + asw[64 + t] + asw[128 + t] + asw[192 + t];
        asum_p[((size_t)b * KK + t) * NT + tile] = a4;
    }
}

// ---------------------------------------------------------------------------
// k_vladm (R13-proven LDS-staged): part[s][b][k][c] =
// sum_{n in chunk} a'[k,n] * x[c,n]   (MFMA, D[k-rows][c-cols])
// A-frag: a_t tile [64k][32n] bf16, staged via linear coalesced uint4.
// B-frag: x tile [64c][32n] bf16, staged via float4 + HW cvt (rows linear).
// Granule-XOR swizzle, double-buffered, 1 barrier/step.
// ---------------------------------------------------------------------------
__global__ __launch_bounds__(256) void k_vladm(const ushort* __restrict__ a_t,
                                               const float* __restrict__ x,
                                               float* __restrict__ part,
                                               int nchunk) {
    int c0 = blockIdx.x * 64;
    int s  = blockIdx.y;
    int b  = blockIdx.z;
    __shared__ __align__(16) ushort Ash[2][64 * 32];  // [k][swz n]
    __shared__ __align__(16) ushort Xsh[2][64 * 32];  // [c][swz n]
    int t = threadIdx.x;
    int lane = t & 63, wv = t >> 6;
    int sk  = t >> 2;              // staging row (k for A, c for X)
    int sn8 = (t & 3) * 8;         // staging n chunk
    const ushort* ab = a_t + (size_t)b * KK * NPIX;
    const float*  xb = x + (size_t)b * CC * NPIX;
    f32x4 acc[4] = {};
    int nbase = s * nchunk;
    int niters = nchunk / 32;

    uint4 ar; float4 x0, x1;
    // ---- prologue
    ar = *(const uint4*)&ab[(size_t)sk * NPIX + nbase + sn8];
    x0 = *(const float4*)&xb[(size_t)(c0 + sk) * NPIX + nbase + sn8];
    x1 = *(const float4*)&xb[(size_t)(c0 + sk) * NPIX + nbase + sn8 + 4];
    {
        uint* AU = (uint*)Ash[0]; uint* XU = (uint*)Xsh[0];
        int gp = (t & 3) ^ ((sk >> 1) & 3);
        *(uint4*)&AU[sk * 16 + gp * 4] = ar;
        uint4 xp;
        xp.x = pk2bf(x0.x, x0.y); xp.y = pk2bf(x0.z, x0.w);
        xp.z = pk2bf(x1.x, x1.y); xp.w = pk2bf(x1.z, x1.w);
        *(uint4*)&XU[sk * 16 + gp * 4] = xp;
    }
    __syncthreads();

    int cur = 0;
    for (int it = 0; it < niters; ++it) {
        bool pre = (it + 1 < niters);
        if (pre) {
            int ng = nbase + (it + 1) * 32;
            ar = *(const uint4*)&ab[(size_t)sk * NPIX + ng + sn8];
            x0 = *(const float4*)&xb[(size_t)(c0 + sk) * NPIX + ng + sn8];
            x1 = *(const float4*)&xb[(size_t)(c0 + sk) * NPIX + ng + sn8 + 4];
        }
        {
            const ushort* Ac = Ash[cur];
            const ushort* Xc = Xsh[cur];
            int rc = wv * 16 + (lane & 15);
            int gB = (lane >> 4) ^ ((rc >> 1) & 3);
            bf16x8 bfr = *(const bf16x8*)&Xc[rc * 32 + gB * 8];
#pragma unroll
            for (int kf = 0; kf < 4; ++kf) {
                int rk = kf * 16 + (lane & 15);
                int gA = (lane >> 4) ^ ((rk >> 1) & 3);
                bf16x8 afr = *(const bf16x8*)&Ac[rk * 32 + gA * 8];
                acc[kf] = MFMA16(afr, bfr, acc[kf], 0, 0, 0);
            }
        }
        if (pre) {
            uint* AU = (uint*)Ash[cur ^ 1]; uint* XU = (uint*)Xsh[cur ^ 1];
            int gp = (t & 3) ^ ((sk >> 1) & 3);
            *(uint4*)&AU[sk * 16 + gp * 4] = ar;
            uint4 xp;
            xp.x = pk2bf(x0.x, x0.y); xp.y = pk2bf(x0.z, x0.w);
            xp.z = pk2bf(x1.x, x1.y); xp.w = pk2bf(x1.z, x1.w);
            *(uint4*)&XU[sk * 16 + gp * 4] = xp;
        }
        __syncthreads();
        cur ^= 1;
    }

    // ---- epilogue: D[k][c] -> part[s][b][k][c]
#pragma unroll
    for (int kf = 0; kf < 4; ++kf)
#pragma unroll
        for (int r = 0; r < 4; ++r) {
            int k = kf * 16 + (lane >> 4) * 4 + r;
            int c = c0 + wv * 16 + (lane & 15);
            part[(((size_t)s * BB + b) * KK + k) * CC + c] = acc[kf][r];
        }
}

// ---------------------------------------------------------------------------
// k_intra: sum ns partials, asum from NT tile-partials, subtract asum*cent,
// intra-normalize per (b,k), accumulate per-b sum of squares.
// ---------------------------------------------------------------------------
__global__ __launch_bounds__(256) void k_intra(const float* __restrict__ part, int ns,
                                               const float* __restrict__ asum_p,
                                               const float* __restrict__ cent,
                                               float* __restrict__ out,
                                               float* __restrict__ bsum) {
    int row = blockIdx.x;                          // b*KK + k
    int b = row >> 6, k = row & 63;
    int t = threadIdx.x;
    float v0 = 0.f, v1 = 0.f;
    for (int s2 = 0; s2 < ns; ++s2) {
        const float* p = part + (((size_t)s2 * BB + b) * KK + k) * CC;
        v0 += p[t];
        v1 += p[t + 256];
    }
    float as = 0.f;
#pragma unroll
    for (int i = 0; i < NT; ++i) as += asum_p[(size_t)row * NT + i];
    v0 -= as * cent[k * CC + t];
    v1 -= as * cent[k * CC + t + 256];
    float ssq = v0 * v0 + v1 * v1;
#pragma unroll
    for (int off = 32; off; off >>= 1) ssq += __shfl_down(ssq, off, 64);
    __shared__ float red[4];
    __shared__ float s_inv;
    if ((t & 63) == 0) red[t >> 6] = ssq;
    __syncthreads();
    if (t == 0) {
        float sm = red[0] + red[1] + red[2] + red[3];
        float inv = 1.f / fmaxf(sqrtf(sm), EPSF);
        s_inv = inv;
        atomicAdd(&bsum[b], sm * inv * inv);
    }
    __syncthreads();
    float inv = s_inv;
    out[(size_t)row * CC + t]       = v0 * inv;
    out[(size_t)row * CC + t + 256] = v1 * inv;
}

// ---------------------------------------------------------------------------
__global__ __launch_bounds__(256) void k_scale(float* __restrict__ out,
                                               const float* __restrict__ bsum) {
    int idx = blockIdx.x * 256 + threadIdx.x;      // B*K*C exact
    int b = idx >> 15;                             // K*C = 32768
    out[idx] *= 1.f / fmaxf(sqrtf(bsum[b]), EPSF);
}

// ---------------------------------------------------------------------------
extern "C" void kernel_launch(void* const* d_in, const int* in_sizes, int n_in,
                              void* d_out, int out_size, void* d_ws, size_t ws_size,
                              hipStream_t stream) {
    const float* x    = (const float*)d_in[0];   // [B,C,H,W]
    const float* cent = (const float*)d_in[1];   // [K,C]
    const float* w    = (const float*)d_in[2];   // [K,C]
    float* out = (float*)d_out;

    char* wsb = (char*)d_ws;
    const size_t oa_at   = 0;                                   // bf16 B*K*N = 6,553,600 B
    const size_t oa_ap   = oa_at + (size_t)BB * KK * NPIX * 2;  // f32 2048*NT =  204,800 B
    const size_t oa_bsum = oa_ap + (size_t)BB * KK * NT * 4;    //                    128 B
    const size_t oa_part = oa_bsum + 128;
    ushort* a_t   = (ushort*)(wsb + oa_at);
    float* asum_p = (float*)(wsb + oa_ap);
    float* bsum   = (float*)(wsb + oa_bsum);

    // pick ns with nchunk = 1600/ns a multiple of 32: {5, 2, 1}
    const size_t pbytes = (size_t)BB * KK * CC * 4;             // 4 MB per partial
    int ns = 0;
    const int cand[3] = {5, 2, 1};
    for (int i = 0; i < 3; ++i) {
        if (oa_part + (size_t)cand[i] * pbytes <= ws_size) { ns = cand[i]; break; }
    }
    float* part = (ns > 0) ? (float*)(wsb + oa_part) : out;     // ns=1 fallback -> d_out
    if (ns == 0) ns = 1;
    int nchunk = NPIX / ns;

    hipMemsetAsync(bsum, 0, BB * sizeof(float), stream);

    k_gemm1m<<<dim3(NT, BB), 256, 0, stream>>>(x, w, a_t, asum_p);
    k_vladm <<<dim3(CC / 64, ns, BB), 256, 0, stream>>>(a_t, x, part, nchunk);
    k_intra <<<dim3(BB * KK), 256, 0, stream>>>(part, ns, asum_p, cent, out, bsum);
    k_scale <<<dim3((BB * KK * CC) / 256), 256, 0, stream>>>(out, bsum);
}

// Round 15
// 88.933 us; speedup vs baseline: 1.4207x; 1.0041x over previous
//
#include <hip/hip_runtime.h>
#include <hip/hip_bf16.h>
#include <math.h>

#define BB   32
#define CC   512
#define NPIX 1600
#define KK   64
#define NT   25        // 64-wide n-tiles in pass A
#define EPSF 1e-12f

typedef __attribute__((ext_vector_type(8))) short bf16x8;
typedef __attribute__((ext_vector_type(4))) float f32x4;
#define MFMA16 __builtin_amdgcn_mfma_f32_16x16x32_bf16

__device__ __forceinline__ ushort f2bf(float f) {
    __hip_bfloat16 h = __float2bfloat16(f);       // RNE, HW cvt
    return *reinterpret_cast<ushort*>(&h);
}
__device__ __forceinline__ uint pk2bf(float a, float b) {
    return (uint)f2bf(a) | ((uint)f2bf(b) << 16);
}

// ---------------------------------------------------------------------------
// k_gemm1m: R14 structure with c-step 64 (two proven 32-c sub-tiles/step):
//   8 iterations (half the barriers), 8 MFMA per barrier, 2-deep prefetch
//   (16 float4 in flight).  MFMA operands from LDS only (R11/R12 lesson).
//   Per (64n tile, b): logits=W@X, ssq->invn, softmax, a'=a*invn -> a_t bf16,
//   asum_p.  Sub-tile layout/swizzle byte-identical to the R13/R14-proven one.
// ---------------------------------------------------------------------------
__global__ __launch_bounds__(256) void k_gemm1m(const float* __restrict__ x,
                                                const float* __restrict__ w,
                                                ushort* __restrict__ a_t,
                                                float* __restrict__ asum_p) {
    int tile = blockIdx.x, b = blockIdx.y;
    int n0 = tile * 64;
    __shared__ __align__(16) ushort Xs[2][2][64 * 32];   // [buf][sub][n][swz c]
    __shared__ __align__(16) ushort Wsh[2][2][64 * 32];  // [buf][sub][k][swz c]
    __shared__ __align__(16) float red[16 * 64];
    __shared__ __align__(16) float asw[4 * 64];
    __shared__ __align__(16) float ivs[64];
    int t = threadIdx.x;
    int lane = t & 63, wv = t >> 6;
    int nlo = lane & 15, khi = lane >> 4;
    int sc2 = (t & 15) * 2;        // X staging: c pair base (0..30) per sub
    int sn4 = (t >> 4) * 4;        // X staging: 4 n rows
    int wk  = t >> 2;              // W staging: k row (0..63)
    int wc8 = (t & 3) * 8;         // W staging: c chunk (8 floats) per sub
    const float* xb = x + (size_t)b * CC * NPIX + n0;
    f32x4 acc[4] = {};
    float ss[4] = {0.f, 0.f, 0.f, 0.f};

    float4 xa[2][2], xc[2][2], wa[2][2], wc2[2][2];   // [slot][sub]

#define LOADQ(it_, sl_)                                                        \
    {                                                                          \
        int cb_ = (it_) * 64;                                                  \
        _Pragma("unroll")                                                      \
        for (int h = 0; h < 2; ++h) {                                          \
            int cs_ = cb_ + h * 32;                                            \
            xa[sl_][h]  = *(const float4*)&xb[(size_t)(cs_ + sc2) * NPIX + sn4];     \
            xc[sl_][h]  = *(const float4*)&xb[(size_t)(cs_ + sc2 + 1) * NPIX + sn4]; \
            wa[sl_][h]  = *(const float4*)&w[(size_t)wk * CC + cs_ + wc8];     \
            wc2[sl_][h] = *(const float4*)&w[(size_t)wk * CC + cs_ + wc8 + 4]; \
        }                                                                      \
    }
#define STOREQ(it_, sl_)                                                       \
    {                                                                          \
        _Pragma("unroll")                                                      \
        for (int h = 0; h < 2; ++h) {                                          \
            uint* XU = (uint*)Xs[(it_) & 1][h];                                \
            uint* WU = (uint*)Wsh[(it_) & 1][h];                               \
            float va_[4] = {xa[sl_][h].x, xa[sl_][h].y, xa[sl_][h].z, xa[sl_][h].w}; \
            float vc_[4] = {xc[sl_][h].x, xc[sl_][h].y, xc[sl_][h].z, xc[sl_][h].w}; \
            _Pragma("unroll")                                                  \
            for (int j = 0; j < 4; ++j) {                                      \
                ss[j] += va_[j] * va_[j] + vc_[j] * vc_[j];                    \
                int row_ = sn4 + j;                                            \
                int gp_ = ((t & 15) >> 2) ^ ((row_ >> 1) & 3);                 \
                XU[row_ * 16 + gp_ * 4 + (t & 3)] = pk2bf(va_[j], vc_[j]);     \
            }                                                                  \
            uint4 wp_;                                                         \
            wp_.x = pk2bf(wa[sl_][h].x,  wa[sl_][h].y);                        \
            wp_.y = pk2bf(wa[sl_][h].z,  wa[sl_][h].w);                        \
            wp_.z = pk2bf(wc2[sl_][h].x, wc2[sl_][h].y);                       \
            wp_.w = pk2bf(wc2[sl_][h].z, wc2[sl_][h].w);                       \
            int gw_ = (t & 3) ^ ((wk >> 1) & 3);                               \
            *(uint4*)&WU[wk * 16 + gw_ * 4] = wp_;                             \
        }                                                                      \
    }

    // ---- prologue: loads for steps 0,1; stage step 0
    LOADQ(0, 0);
    LOADQ(1, 1);
    STOREQ(0, 0);
    __syncthreads();

#pragma unroll
    for (int it = 0; it < 8; ++it) {
        if (it + 2 < 8) LOADQ(it + 2, it & 1);
        // ---- MFMA on current buffer (operands from LDS only)
        {
            int buf = it & 1;
            int rn = wv * 16 + nlo;
            int gB = khi ^ ((rn >> 1) & 3);
            bf16x8 b0 = *(const bf16x8*)&Xs[buf][0][rn * 32 + gB * 8];
            bf16x8 b1 = *(const bf16x8*)&Xs[buf][1][rn * 32 + gB * 8];
#pragma unroll
            for (int kf = 0; kf < 4; ++kf) {
                int rk = kf * 16 + nlo;
                int gA = khi ^ ((rk >> 1) & 3);
                bf16x8 a0 = *(const bf16x8*)&Wsh[buf][0][rk * 32 + gA * 8];
                acc[kf] = MFMA16(a0, b0, acc[kf], 0, 0, 0);
                bf16x8 a1 = *(const bf16x8*)&Wsh[buf][1][rk * 32 + gA * 8];
                acc[kf] = MFMA16(a1, b1, acc[kf], 0, 0, 0);
            }
        }
        if (it + 1 < 8) STOREQ(it + 1, (it + 1) & 1);
        __syncthreads();
    }
#undef LOADQ
#undef STOREQ

    // ---- ssq reduce -> invn (LDS only)
#pragma unroll
    for (int j = 0; j < 4; ++j) red[(t & 15) * 64 + sn4 + j] = ss[j];
    __syncthreads();
    if (t < 64) {
        float s = 0.f;
#pragma unroll
        for (int i = 0; i < 16; ++i) s += red[i * 64 + t];
        ivs[t] = 1.f / fmaxf(sqrtf(s), EPSF);
    }
    __syncthreads();

    int nloc = wv * 16 + nlo;
    float invl = ivs[nloc];

    // ---- softmax over k (lane holds 16 k's for one n; combine khi groups)
    float lv[4][4];
    float mm = -1e30f;
#pragma unroll
    for (int kf = 0; kf < 4; ++kf)
#pragma unroll
        for (int r = 0; r < 4; ++r) {
            lv[kf][r] = acc[kf][r] * invl;
            mm = fmaxf(mm, lv[kf][r]);
        }
    mm = fmaxf(mm, __shfl_xor(mm, 16));
    mm = fmaxf(mm, __shfl_xor(mm, 32));
    float ev[4][4], s = 0.f;
#pragma unroll
    for (int kf = 0; kf < 4; ++kf)
#pragma unroll
        for (int r = 0; r < 4; ++r) {
            ev[kf][r] = expf(lv[kf][r] - mm);
            s += ev[kf][r];
        }
    s += __shfl_xor(s, 16);
    s += __shfl_xor(s, 32);
    float sd = 1.f / s;

    // ---- asum partials (unscaled a): reduce over the wave's 16 n
    float av[4][4];
#pragma unroll
    for (int kf = 0; kf < 4; ++kf)
#pragma unroll
        for (int r = 0; r < 4; ++r) av[kf][r] = ev[kf][r] * sd;
#pragma unroll
    for (int off = 1; off < 16; off <<= 1)
#pragma unroll
        for (int kf = 0; kf < 4; ++kf)
#pragma unroll
            for (int r = 0; r < 4; ++r) av[kf][r] += __shfl_xor(av[kf][r], off);
    if (nlo == 0) {
#pragma unroll
        for (int kf = 0; kf < 4; ++kf)
#pragma unroll
            for (int r = 0; r < 4; ++r)
                asw[wv * 64 + kf * 16 + khi * 4 + r] = av[kf][r];
    }

    // ---- a' = a * invn -> a_t[b][k][n] bf16
    ushort* ab = a_t + (size_t)b * KK * NPIX;
#pragma unroll
    for (int kf = 0; kf < 4; ++kf)
#pragma unroll
        for (int r = 0; r < 4; ++r) {
            int k = kf * 16 + khi * 4 + r;
            ab[(size_t)k * NPIX + n0 + nloc] = f2bf(ev[kf][r] * sd * invl);
        }
    __syncthreads();
    if (t < 64) {
        float a4 = asw[t] + asw[64 + t] + asw[128 + t] + asw[192 + t];
        asum_p[((size_t)b * KK + t) * NT + tile] = a4;
    }
}

// ---------------------------------------------------------------------------
// k_vladm (R13/R14-proven LDS-staged): part[s][b][k][c] =
// sum_{n in chunk} a'[k,n] * x[c,n]   (MFMA, D[k-rows][c-cols])
// A-frag: a_t tile [64k][32n] bf16, staged via linear coalesced uint4.
// B-frag: x tile [64c][32n] bf16, staged via float4 + HW cvt (rows linear).
// Granule-XOR swizzle, double-buffered, 1 barrier/step.
// ---------------------------------------------------------------------------
__global__ __launch_bounds__(256) void k_vladm(const ushort* __restrict__ a_t,
                                               const float* __restrict__ x,
                                               float* __restrict__ part,
                                               int nchunk) {
    int c0 = blockIdx.x * 64;
    int s  = blockIdx.y;
    int b  = blockIdx.z;
    __shared__ __align__(16) ushort Ash[2][64 * 32];  // [k][swz n]
    __shared__ __align__(16) ushort Xsh[2][64 * 32];  // [c][swz n]
    int t = threadIdx.x;
    int lane = t & 63, wv = t >> 6;
    int sk  = t >> 2;              // staging row (k for A, c for X)
    int sn8 = (t & 3) * 8;         // staging n chunk
    const ushort* ab = a_t + (size_t)b * KK * NPIX;
    const float*  xb = x + (size_t)b * CC * NPIX;
    f32x4 acc[4] = {};
    int nbase = s * nchunk;
    int niters = nchunk / 32;

    uint4 ar; float4 x0, x1;
    // ---- prologue
    ar = *(const uint4*)&ab[(size_t)sk * NPIX + nbase + sn8];
    x0 = *(const float4*)&xb[(size_t)(c0 + sk) * NPIX + nbase + sn8];
    x1 = *(const float4*)&xb[(size_t)(c0 + sk) * NPIX + nbase + sn8 + 4];
    {
        uint* AU = (uint*)Ash[0]; uint* XU = (uint*)Xsh[0];
        int gp = (t & 3) ^ ((sk >> 1) & 3);
        *(uint4*)&AU[sk * 16 + gp * 4] = ar;
        uint4 xp;
        xp.x = pk2bf(x0.x, x0.y); xp.y = pk2bf(x0.z, x0.w);
        xp.z = pk2bf(x1.x, x1.y); xp.w = pk2bf(x1.z, x1.w);
        *(uint4*)&XU[sk * 16 + gp * 4] = xp;
    }
    __syncthreads();

    int cur = 0;
    for (int it = 0; it < niters; ++it) {
        bool pre = (it + 1 < niters);
        if (pre) {
            int ng = nbase + (it + 1) * 32;
            ar = *(const uint4*)&ab[(size_t)sk * NPIX + ng + sn8];
            x0 = *(const float4*)&xb[(size_t)(c0 + sk) * NPIX + ng + sn8];
            x1 = *(const float4*)&xb[(size_t)(c0 + sk) * NPIX + ng + sn8 + 4];
        }
        {
            const ushort* Ac = Ash[cur];
            const ushort* Xc = Xsh[cur];
            int rc = wv * 16 + (lane & 15);
            int gB = (lane >> 4) ^ ((rc >> 1) & 3);
            bf16x8 bfr = *(const bf16x8*)&Xc[rc * 32 + gB * 8];
#pragma unroll
            for (int kf = 0; kf < 4; ++kf) {
                int rk = kf * 16 + (lane & 15);
                int gA = (lane >> 4) ^ ((rk >> 1) & 3);
                bf16x8 afr = *(const bf16x8*)&Ac[rk * 32 + gA * 8];
                acc[kf] = MFMA16(afr, bfr, acc[kf], 0, 0, 0);
            }
        }
        if (pre) {
            uint* AU = (uint*)Ash[cur ^ 1]; uint* XU = (uint*)Xsh[cur ^ 1];
            int gp = (t & 3) ^ ((sk >> 1) & 3);
            *(uint4*)&AU[sk * 16 + gp * 4] = ar;
            uint4 xp;
            xp.x = pk2bf(x0.x, x0.y); xp.y = pk2bf(x0.z, x0.w);
            xp.z = pk2bf(x1.x, x1.y); xp.w = pk2bf(x1.z, x1.w);
            *(uint4*)&XU[sk * 16 + gp * 4] = xp;
        }
        __syncthreads();
        cur ^= 1;
    }

    // ---- epilogue: D[k][c] -> part[s][b][k][c]
#pragma unroll
    for (int kf = 0; kf < 4; ++kf)
#pragma unroll
        for (int r = 0; r < 4; ++r) {
            int k = kf * 16 + (lane >> 4) * 4 + r;
            int c = c0 + wv * 16 + (lane & 15);
            part[(((size_t)s * BB + b) * KK + k) * CC + c] = acc[kf][r];
        }
}

// ---------------------------------------------------------------------------
// k_intra: sum ns partials, asum from NT tile-partials, subtract asum*cent,
// intra-normalize per (b,k), accumulate per-b sum of squares.
// ---------------------------------------------------------------------------
__global__ __launch_bounds__(256) void k_intra(const float* __restrict__ part, int ns,
                                               const float* __restrict__ asum_p,
                                               const float* __restrict__ cent,
                                               float* __restrict__ out,
                                               float* __restrict__ bsum) {
    int row = blockIdx.x;                          // b*KK + k
    int b = row >> 6, k = row & 63;
    int t = threadIdx.x;
    float v0 = 0.f, v1 = 0.f;
    for (int s2 = 0; s2 < ns; ++s2) {
        const float* p = part + (((size_t)s2 * BB + b) * KK + k) * CC;
        v0 += p[t];
        v1 += p[t + 256];
    }
    float as = 0.f;
#pragma unroll
    for (int i = 0; i < NT; ++i) as += asum_p[(size_t)row * NT + i];
    v0 -= as * cent[k * CC + t];
    v1 -= as * cent[k * CC + t + 256];
    float ssq = v0 * v0 + v1 * v1;
#pragma unroll
    for (int off = 32; off; off >>= 1) ssq += __shfl_down(ssq, off, 64);
    __shared__ float red[4];
    __shared__ float s_inv;
    if ((t & 63) == 0) red[t >> 6] = ssq;
    __syncthreads();
    if (t == 0) {
        float sm = red[0] + red[1] + red[2] + red[3];
        float inv = 1.f / fmaxf(sqrtf(sm), EPSF);
        s_inv = inv;
        atomicAdd(&bsum[b], sm * inv * inv);
    }
    __syncthreads();
    float inv = s_inv;
    out[(size_t)row * CC + t]       = v0 * inv;
    out[(size_t)row * CC + t + 256] = v1 * inv;
}

// ---------------------------------------------------------------------------
__global__ __launch_bounds__(256) void k_scale(float* __restrict__ out,
                                               const float* __restrict__ bsum) {
    int idx = blockIdx.x * 256 + threadIdx.x;      // B*K*C exact
    int b = idx >> 15;                             // K*C = 32768
    out[idx] *= 1.f / fmaxf(sqrtf(bsum[b]), EPSF);
}

// ---------------------------------------------------------------------------
extern "C" void kernel_launch(void* const* d_in, const int* in_sizes, int n_in,
                              void* d_out, int out_size, void* d_ws, size_t ws_size,
                              hipStream_t stream) {
    const float* x    = (const float*)d_in[0];   // [B,C,H,W]
    const float* cent = (const float*)d_in[1];   // [K,C]
    const float* w    = (const float*)d_in[2];   // [K,C]
    float* out = (float*)d_out;

    char* wsb = (char*)d_ws;
    const size_t oa_at   = 0;                                   // bf16 B*K*N = 6,553,600 B
    const size_t oa_ap   = oa_at + (size_t)BB * KK * NPIX * 2;  // f32 2048*NT =  204,800 B
    const size_t oa_bsum = oa_ap + (size_t)BB * KK * NT * 4;    //                    128 B
    const size_t oa_part = oa_bsum + 128;
    ushort* a_t   = (ushort*)(wsb + oa_at);
    float* asum_p = (float*)(wsb + oa_ap);
    float* bsum   = (float*)(wsb + oa_bsum);

    // pick ns with nchunk = 1600/ns a multiple of 32: {5, 2, 1}
    const size_t pbytes = (size_t)BB * KK * CC * 4;             // 4 MB per partial
    int ns = 0;
    const int cand[3] = {5, 2, 1};
    for (int i = 0; i < 3; ++i) {
        if (oa_part + (size_t)cand[i] * pbytes <= ws_size) { ns = cand[i]; break; }
    }
    float* part = (ns > 0) ? (float*)(wsb + oa_part) : out;     // ns=1 fallback -> d_out
    if (ns == 0) ns = 1;
    int nchunk = NPIX / ns;

    hipMemsetAsync(bsum, 0, BB * sizeof(float), stream);

    k_gemm1m<<<dim3(NT, BB), 256, 0, stream>>>(x, w, a_t, asum_p);
    k_vladm <<<dim3(CC / 64, ns, BB), 256, 0, stream>>>(a_t, x, part, nchunk);
    k_intra <<<dim3(BB * KK), 256, 0, stream>>>(part, ns, asum_p, cent, out, bsum);
    k_scale <<<dim3((BB * KK * CC) / 256), 256, 0, stream>>>(out, bsum);
}